// Round 1
// baseline (1314.210 us; speedup 1.0000x reference)
//
#include <hip/hip_runtime.h>
#include <math.h>

// Shapes (fixed for this problem)
#define BB 8
#define HH 64
#define WW 64
#define CC 256          // outer channels
#define CI 128          // inner channels
#define NN 4096         // H*W
#define NS 2048         // H*(W/2)
#define BNEPS 1e-3f

__device__ __forceinline__ float eluf(float v) { return v > 0.f ? v : expm1f(v); }

// ---------------- Kernel A: x = elu(bn1(inputs)) ----------------
// 8*64*64*256 = 8388608 floats = 2097152 float4; grid 8192 x 256 exact.
__global__ __launch_bounds__(256) void k_bn1_elu(
    const float* __restrict__ in, const float* __restrict__ gamma,
    const float* __restrict__ beta, const float* __restrict__ mean,
    const float* __restrict__ var, float* __restrict__ x)
{
  int i = blockIdx.x * blockDim.x + threadIdx.x;   // float4 index
  float4 v = ((const float4*)in)[i];
  int c0 = (i << 2) & (CC - 1);
  float vv[4] = {v.x, v.y, v.z, v.w};
  float o[4];
#pragma unroll
  for (int j = 0; j < 4; ++j) {
    int c = c0 + j;
    float s = gamma[c] * rsqrtf(var[c] + BNEPS);
    o[j] = eluf((vv[j] - mean[c]) * s + beta[c]);
  }
  float4 r = {o[0], o[1], o[2], o[3]};
  ((float4*)x)[i] = r;
}

// ---------------- Kernel B: out = x @ W + b  (M=32768, K=256, N=128) ----------------
// BM=64, BN=128 (full), BK=32, 256 threads, 4x8 micro-tile per thread.
__global__ __launch_bounds__(256) void k_gemm_xw(
    const float* __restrict__ x, const float* __restrict__ Wt,
    const float* __restrict__ bias, float* __restrict__ out)
{
  __shared__ float xs[64][33];
  __shared__ float ws[32][128];
  const int bm = blockIdx.x * 64;
  const int tid = threadIdx.x;
  const int ty = tid >> 4, tx = tid & 15;
  float acc[4][8];
#pragma unroll
  for (int i = 0; i < 4; ++i)
#pragma unroll
    for (int j = 0; j < 8; ++j) acc[i][j] = 0.f;

  for (int k0 = 0; k0 < CC; k0 += 32) {
#pragma unroll
    for (int j = 0; j < 2; ++j) {
      int f = tid * 2 + j;
      int r = f >> 3, cf = f & 7;
      float4 v = *(const float4*)&x[(size_t)(bm + r) * CC + k0 + (cf << 2)];
      xs[r][(cf << 2) + 0] = v.x; xs[r][(cf << 2) + 1] = v.y;
      xs[r][(cf << 2) + 2] = v.z; xs[r][(cf << 2) + 3] = v.w;
    }
#pragma unroll
    for (int j = 0; j < 4; ++j) {
      int f = tid * 4 + j;
      int r = f >> 5, c4 = f & 31;
      *(float4*)&ws[r][c4 << 2] = *(const float4*)&Wt[(size_t)(k0 + r) * CI + (c4 << 2)];
    }
    __syncthreads();
#pragma unroll 8
    for (int k = 0; k < 32; ++k) {
      float a[4];
#pragma unroll
      for (int i = 0; i < 4; ++i) a[i] = xs[(ty << 2) + i][k];
      float4 b0 = *(float4*)&ws[k][tx << 3];
      float4 b1 = *(float4*)&ws[k][(tx << 3) + 4];
      float bb[8] = {b0.x, b0.y, b0.z, b0.w, b1.x, b1.y, b1.z, b1.w};
#pragma unroll
      for (int i = 0; i < 4; ++i)
#pragma unroll
        for (int j = 0; j < 8; ++j) acc[i][j] = fmaf(a[i], bb[j], acc[i][j]);
    }
    __syncthreads();
  }
#pragma unroll
  for (int i = 0; i < 4; ++i) {
    size_t row = bm + (ty << 2) + i;
    int col = tx << 3;
    float4 o0 = {acc[i][0] + bias[col + 0], acc[i][1] + bias[col + 1],
                 acc[i][2] + bias[col + 2], acc[i][3] + bias[col + 3]};
    float4 o1 = {acc[i][4] + bias[col + 4], acc[i][5] + bias[col + 5],
                 acc[i][6] + bias[col + 6], acc[i][7] + bias[col + 7]};
    *(float4*)&out[row * CI + col] = o0;
    *(float4*)&out[row * CI + col + 4] = o1;
  }
}

// ---------------- Kernel C: width-2 maxpool for g and phi ----------------
// pooled: 8*2048*128 = 2097152 floats = 524288 float4; grid 2048 x 256 exact.
__global__ __launch_bounds__(256) void k_pool(
    const float* __restrict__ Gf, const float* __restrict__ Pf,
    float* __restrict__ Gp, float* __restrict__ Pp)
{
  int i = blockIdx.x * blockDim.x + threadIdx.x;  // float4 idx
  int d4 = i & 31;            // 32 float4 per row of 128
  int pr = i >> 5;            // pooled row
  int wq = pr & 31, hh = (pr >> 5) & 63, b = pr >> 11;
  size_t fr = ((size_t)b * NN + hh * 64 + (wq << 1)) * 32 + d4;
  float4 a = ((const float4*)Gf)[fr];
  float4 c = ((const float4*)Gf)[fr + 32];
  float4 r1 = {fmaxf(a.x, c.x), fmaxf(a.y, c.y), fmaxf(a.z, c.z), fmaxf(a.w, c.w)};
  ((float4*)Gp)[i] = r1;
  a = ((const float4*)Pf)[fr];
  c = ((const float4*)Pf)[fr + 32];
  float4 r2 = {fmaxf(a.x, c.x), fmaxf(a.y, c.y), fmaxf(a.z, c.z), fmaxf(a.w, c.w)};
  ((float4*)Pp)[i] = r2;
}

// ---------------- Kernel D: flash attention (no f materialization) ----------------
// Per block: batch b, 32 theta rows; loop Ns in tiles of 32 with online softmax.
__global__ __launch_bounds__(256) void k_attn(
    const float* __restrict__ T, const float* __restrict__ Pp,
    const float* __restrict__ Gp, float* __restrict__ Y)
{
  __shared__ float th[32][132];
  __shared__ float ph[32][132];
  __shared__ float gs[32][132];
  __shared__ float Sb[32][33];
  __shared__ float mrow[32], lrow[32], arow[32];
  const int b = blockIdx.y;
  const int r0 = blockIdx.x << 5;
  const float* Tb = T + ((size_t)b * NN + r0) * CI;
  const float* Pb = Pp + (size_t)b * NS * CI;
  const float* Gb = Gp + (size_t)b * NS * CI;
  const int tid = threadIdx.x;
  const int ty = tid >> 4, tx = tid & 15;

#pragma unroll
  for (int j = 0; j < 4; ++j) {
    int f = (tid << 2) + j;
    int r = f >> 5, c4 = f & 31;
    float4 v = *(const float4*)&Tb[r * CI + (c4 << 2)];
    th[r][(c4 << 2) + 0] = v.x; th[r][(c4 << 2) + 1] = v.y;
    th[r][(c4 << 2) + 2] = v.z; th[r][(c4 << 2) + 3] = v.w;
  }
  if (tid < 32) { mrow[tid] = -3.0e38f; lrow[tid] = 0.f; }
  float acc[2][2][4];
#pragma unroll
  for (int r = 0; r < 2; ++r)
#pragma unroll
    for (int g = 0; g < 2; ++g)
#pragma unroll
      for (int j = 0; j < 4; ++j) acc[r][g][j] = 0.f;
  __syncthreads();

  for (int t = 0; t < NS; t += 32) {
#pragma unroll
    for (int j = 0; j < 4; ++j) {
      int f = (tid << 2) + j;
      int r = f >> 5, c4 = f & 31;
      float4 v = *(const float4*)&Pb[(size_t)(t + r) * CI + (c4 << 2)];
      ph[r][(c4 << 2) + 0] = v.x; ph[r][(c4 << 2) + 1] = v.y;
      ph[r][(c4 << 2) + 2] = v.z; ph[r][(c4 << 2) + 3] = v.w;
      float4 w = *(const float4*)&Gb[(size_t)(t + r) * CI + (c4 << 2)];
      gs[r][(c4 << 2) + 0] = w.x; gs[r][(c4 << 2) + 1] = w.y;
      gs[r][(c4 << 2) + 2] = w.z; gs[r][(c4 << 2) + 3] = w.w;
    }
    __syncthreads();

    // S = theta_block @ phi_tile^T : 2x2 per thread
    float s00 = 0.f, s01 = 0.f, s10 = 0.f, s11 = 0.f;
#pragma unroll 8
    for (int k4 = 0; k4 < 32; ++k4) {
      float4 a0 = *(float4*)&th[ty][k4 << 2];
      float4 a1 = *(float4*)&th[ty + 16][k4 << 2];
      float4 p0 = *(float4*)&ph[tx][k4 << 2];
      float4 p1 = *(float4*)&ph[tx + 16][k4 << 2];
      s00 += a0.x * p0.x + a0.y * p0.y + a0.z * p0.z + a0.w * p0.w;
      s01 += a0.x * p1.x + a0.y * p1.y + a0.z * p1.z + a0.w * p1.w;
      s10 += a1.x * p0.x + a1.y * p0.y + a1.z * p0.z + a1.w * p0.w;
      s11 += a1.x * p1.x + a1.y * p1.y + a1.z * p1.z + a1.w * p1.w;
    }
    Sb[ty][tx] = s00; Sb[ty][tx + 16] = s01;
    Sb[ty + 16][tx] = s10; Sb[ty + 16][tx + 16] = s11;
    __syncthreads();

    if (tid < 32) {
      float mold = mrow[tid];
      float mx = mold;
#pragma unroll 8
      for (int c = 0; c < 32; ++c) mx = fmaxf(mx, Sb[tid][c]);
      float al = __expf(mold - mx);
      float s = 0.f;
#pragma unroll 8
      for (int c = 0; c < 32; ++c) s += __expf(Sb[tid][c] - mx);
      lrow[tid] = lrow[tid] * al + s;
      mrow[tid] = mx;
      arow[tid] = al;
    }
    __syncthreads();

    float m0 = mrow[ty], m1 = mrow[ty + 16];
    float al0 = arow[ty], al1 = arow[ty + 16];
    Sb[ty][tx] = __expf(s00 - m0); Sb[ty][tx + 16] = __expf(s01 - m0);
    Sb[ty + 16][tx] = __expf(s10 - m1); Sb[ty + 16][tx + 16] = __expf(s11 - m1);
#pragma unroll
    for (int g = 0; g < 2; ++g)
#pragma unroll
      for (int j = 0; j < 4; ++j) { acc[0][g][j] *= al0; acc[1][g][j] *= al1; }
    __syncthreads();

    // acc += P @ g_tile
#pragma unroll 4
    for (int c = 0; c < 32; ++c) {
      float q0 = Sb[ty][c], q1 = Sb[ty + 16][c];
      float4 g0 = *(float4*)&gs[c][tx << 2];
      float4 g1 = *(float4*)&gs[c][64 + (tx << 2)];
      float gg0[4] = {g0.x, g0.y, g0.z, g0.w};
      float gg1[4] = {g1.x, g1.y, g1.z, g1.w};
#pragma unroll
      for (int j = 0; j < 4; ++j) {
        acc[0][0][j] = fmaf(q0, gg0[j], acc[0][0][j]);
        acc[0][1][j] = fmaf(q0, gg1[j], acc[0][1][j]);
        acc[1][0][j] = fmaf(q1, gg0[j], acc[1][0][j]);
        acc[1][1][j] = fmaf(q1, gg1[j], acc[1][1][j]);
      }
    }
    __syncthreads();
  }

  float inv0 = 1.f / lrow[ty];
  float inv1 = 1.f / lrow[ty + 16];
  size_t base0 = ((size_t)b * NN + r0 + ty) * CI;
  size_t base1 = ((size_t)b * NN + r0 + ty + 16) * CI;
  float4 o;
  o = {acc[0][0][0] * inv0, acc[0][0][1] * inv0, acc[0][0][2] * inv0, acc[0][0][3] * inv0};
  *(float4*)&Y[base0 + (tx << 2)] = o;
  o = {acc[0][1][0] * inv0, acc[0][1][1] * inv0, acc[0][1][2] * inv0, acc[0][1][3] * inv0};
  *(float4*)&Y[base0 + 64 + (tx << 2)] = o;
  o = {acc[1][0][0] * inv1, acc[1][0][1] * inv1, acc[1][0][2] * inv1, acc[1][0][3] * inv1};
  *(float4*)&Y[base1 + (tx << 2)] = o;
  o = {acc[1][1][0] * inv1, acc[1][1][1] * inv1, acc[1][1][2] * inv1, acc[1][1][3] * inv1};
  *(float4*)&Y[base1 + 64 + (tx << 2)] = o;
}

// ---------------- Kernel E: out = (elu(bn2(Y)) @ Wz + bz) * sita + inputs ----------------
// M=32768, K=128, N=256; BM=64, BN=128, BK=32; grid (512, 2).
__global__ __launch_bounds__(256) void k_gemm_z(
    const float* __restrict__ Y, const float* __restrict__ Wz,
    const float* __restrict__ bz, const float* __restrict__ g2,
    const float* __restrict__ be2, const float* __restrict__ mu2,
    const float* __restrict__ var2, const float* __restrict__ inp,
    const float* __restrict__ sita, float* __restrict__ out)
{
  __shared__ float ysm[64][33];
  __shared__ float ws[32][128];
  const int bm = blockIdx.x * 64;
  const int n0 = blockIdx.y * 128;
  const int tid = threadIdx.x;
  const int ty = tid >> 4, tx = tid & 15;
  float acc[4][8];
#pragma unroll
  for (int i = 0; i < 4; ++i)
#pragma unroll
    for (int j = 0; j < 8; ++j) acc[i][j] = 0.f;

  for (int k0 = 0; k0 < CI; k0 += 32) {
#pragma unroll
    for (int j = 0; j < 2; ++j) {
      int f = tid * 2 + j;
      int r = f >> 3, cf = f & 7;
      float4 v = *(const float4*)&Y[(size_t)(bm + r) * CI + k0 + (cf << 2)];
      float vv[4] = {v.x, v.y, v.z, v.w};
#pragma unroll
      for (int u = 0; u < 4; ++u) {
        int ch = k0 + (cf << 2) + u;
        float s = g2[ch] * rsqrtf(var2[ch] + BNEPS);
        ysm[r][(cf << 2) + u] = eluf((vv[u] - mu2[ch]) * s + be2[ch]);
      }
    }
#pragma unroll
    for (int j = 0; j < 4; ++j) {
      int f = tid * 4 + j;
      int r = f >> 5, c4 = f & 31;
      *(float4*)&ws[r][c4 << 2] = *(const float4*)&Wz[(size_t)(k0 + r) * CC + n0 + (c4 << 2)];
    }
    __syncthreads();
#pragma unroll 8
    for (int k = 0; k < 32; ++k) {
      float a[4];
#pragma unroll
      for (int i = 0; i < 4; ++i) a[i] = ysm[(ty << 2) + i][k];
      float4 b0 = *(float4*)&ws[k][tx << 3];
      float4 b1 = *(float4*)&ws[k][(tx << 3) + 4];
      float bb[8] = {b0.x, b0.y, b0.z, b0.w, b1.x, b1.y, b1.z, b1.w};
#pragma unroll
      for (int i = 0; i < 4; ++i)
#pragma unroll
        for (int j = 0; j < 8; ++j) acc[i][j] = fmaf(a[i], bb[j], acc[i][j]);
    }
    __syncthreads();
  }
  float st = sita[0];
#pragma unroll
  for (int i = 0; i < 4; ++i) {
    size_t row = bm + (ty << 2) + i;
    int col = n0 + (tx << 3);
    float4 i0 = *(const float4*)&inp[row * CC + col];
    float4 i1 = *(const float4*)&inp[row * CC + col + 4];
    float4 o0 = {(acc[i][0] + bz[col + 0]) * st + i0.x,
                 (acc[i][1] + bz[col + 1]) * st + i0.y,
                 (acc[i][2] + bz[col + 2]) * st + i0.z,
                 (acc[i][3] + bz[col + 3]) * st + i0.w};
    float4 o1 = {(acc[i][4] + bz[col + 4]) * st + i1.x,
                 (acc[i][5] + bz[col + 5]) * st + i1.y,
                 (acc[i][6] + bz[col + 6]) * st + i1.z,
                 (acc[i][7] + bz[col + 7]) * st + i1.w};
    *(float4*)&out[row * CC + col] = o0;
    *(float4*)&out[row * CC + col + 4] = o1;
  }
}

extern "C" void kernel_launch(void* const* d_in, const int* in_sizes, int n_in,
                              void* d_out, int out_size, void* d_ws, size_t ws_size,
                              hipStream_t stream) {
  const float* inp      = (const float*)d_in[0];
  const float* bn1_g    = (const float*)d_in[1];
  const float* bn1_b    = (const float*)d_in[2];
  const float* bn1_m    = (const float*)d_in[3];
  const float* bn1_v    = (const float*)d_in[4];
  const float* bn2_g    = (const float*)d_in[5];
  const float* bn2_b    = (const float*)d_in[6];
  const float* bn2_m    = (const float*)d_in[7];
  const float* bn2_v    = (const float*)d_in[8];
  const float* W_g      = (const float*)d_in[9];
  const float* b_g      = (const float*)d_in[10];
  const float* W_theta  = (const float*)d_in[11];
  const float* b_theta  = (const float*)d_in[12];
  const float* W_phi    = (const float*)d_in[13];
  const float* b_phi    = (const float*)d_in[14];
  const float* W_z      = (const float*)d_in[15];
  const float* b_z      = (const float*)d_in[16];
  const float* sita     = (const float*)d_in[17];
  float* out = (float*)d_out;

  // Workspace layout (floats):
  float* ws_f = (float*)d_ws;
  float* x  = ws_f;                 // 8388608
  float* T  = x + 8388608;          // 4194304
  float* Gf = T + 4194304;          // 4194304 (reused as Y after pooling)
  float* Pf = Gf + 4194304;         // 4194304
  float* Gp = Pf + 4194304;         // 2097152
  float* Pp = Gp + 2097152;         // 2097152
  float* Yb = Gf;                   // alias: raw g no longer needed after k_pool

  k_bn1_elu<<<dim3(8192), dim3(256), 0, stream>>>(inp, bn1_g, bn1_b, bn1_m, bn1_v, x);
  k_gemm_xw<<<dim3(512), dim3(256), 0, stream>>>(x, W_theta, b_theta, T);
  k_gemm_xw<<<dim3(512), dim3(256), 0, stream>>>(x, W_g, b_g, Gf);
  k_gemm_xw<<<dim3(512), dim3(256), 0, stream>>>(x, W_phi, b_phi, Pf);
  k_pool<<<dim3(2048), dim3(256), 0, stream>>>(Gf, Pf, Gp, Pp);
  k_attn<<<dim3(128, 8), dim3(256), 0, stream>>>(T, Pp, Gp, Yb);
  k_gemm_z<<<dim3(512, 2), dim3(256), 0, stream>>>(Yb, W_z, b_z, bn2_g, bn2_b, bn2_m, bn2_v,
                                                   inp, sita, out);
}

// Round 2
// 348.769 us; speedup vs baseline: 3.7681x; 3.7681x over previous
//
#include <hip/hip_runtime.h>
#include <math.h>

#define BNEPS 1e-3f

typedef __attribute__((ext_vector_type(8))) short bf8;
typedef __attribute__((ext_vector_type(8))) unsigned short u16x8;
typedef __attribute__((ext_vector_type(16))) float f32x16;

__device__ __forceinline__ unsigned short f2bf(float x) {
  unsigned u = __builtin_bit_cast(unsigned, x);
  unsigned r = (u + 0x7fffu + ((u >> 16) & 1u)) >> 16;
  return (unsigned short)r;
}
__device__ __forceinline__ float bf2f(unsigned short h) {
  return __builtin_bit_cast(float, ((unsigned)h) << 16);
}
__device__ __forceinline__ float eluf(float v) { return v > 0.f ? v : expm1f(v); }
__device__ __forceinline__ unsigned pk2(float a, float b) {
  return (unsigned)f2bf(a) | ((unsigned)f2bf(b) << 16);
}

// ---------- prep: transpose+cast weights to bf16 [N][K]; bn2 scale/shift ----------
__global__ __launch_bounds__(256) void k_prepw(
    const float* __restrict__ Wth, const float* __restrict__ Wg,
    const float* __restrict__ Wph, const float* __restrict__ Wz,
    const float* __restrict__ g2, const float* __restrict__ be2,
    const float* __restrict__ mu2, const float* __restrict__ v2,
    unsigned short* __restrict__ Wt3, unsigned short* __restrict__ Wzt,
    float* __restrict__ bn2s, float* __restrict__ bn2h)
{
  int id = blockIdx.x * 256 + threadIdx.x;
  if (id < 98304) {
    int w = id >> 15, rem = id & 32767;
    int n = rem >> 8, k = rem & 255;
    const float* W = (w == 0) ? Wth : (w == 1) ? Wg : Wph;
    Wt3[id] = f2bf(W[(size_t)k * 128 + n]);
  } else {
    int rem = id - 98304;
    int n = rem >> 7, k = rem & 127;
    Wzt[rem] = f2bf(Wz[(size_t)k * 256 + n]);
  }
  if (id < 128) {
    float s = g2[id] * rsqrtf(v2[id] + BNEPS);
    bn2s[id] = s;
    bn2h[id] = be2[id] - mu2[id] * s;
  }
}

// ---------- bn1 + elu -> bf16 x ----------
__global__ __launch_bounds__(256) void k_bn1(
    const float* __restrict__ in, const float* __restrict__ gm,
    const float* __restrict__ bt, const float* __restrict__ mu,
    const float* __restrict__ vr, unsigned short* __restrict__ x)
{
  int i = blockIdx.x * 256 + threadIdx.x;  // 8 elems each
  const float4* p = (const float4*)(in + (size_t)i * 8);
  float4 a = p[0], c = p[1];
  int c0 = (i * 8) & 255;
  float vals[8] = {a.x, a.y, a.z, a.w, c.x, c.y, c.z, c.w};
  u16x8 o;
#pragma unroll
  for (int j = 0; j < 8; ++j) {
    int ch = c0 + j;
    float s = gm[ch] * rsqrtf(vr[ch] + BNEPS);
    o[j] = f2bf(eluf((vals[j] - mu[ch]) * s + bt[ch]));
  }
  *(u16x8*)(x + (size_t)i * 8) = o;
}

// ---------- 3-in-1 MFMA GEMM: out = bf16(x @ W + b), M=32768 K=256 N=128 ----------
__global__ __launch_bounds__(256) void k_gemm3(
    const unsigned short* __restrict__ xbf, const unsigned short* __restrict__ Wt3,
    const float* __restrict__ bth, const float* __restrict__ bg,
    const float* __restrict__ bph, unsigned short* __restrict__ Tb,
    unsigned short* __restrict__ Gf, unsigned short* __restrict__ Pf)
{
  __shared__ unsigned short As[128][72];
  __shared__ unsigned short Bs[128][72];
  const int bm = blockIdx.x * 128;
  const int sel = blockIdx.y;
  const unsigned short* W = Wt3 + (size_t)sel * 32768;
  const float* bias = (sel == 0) ? bth : (sel == 1) ? bg : bph;
  unsigned short* out = (sel == 0) ? Tb : (sel == 1) ? Gf : Pf;
  const int tid = threadIdx.x;
  const int l = tid & 63, w = tid >> 6;
  const int lo = l & 31, g = l >> 5;
  const int row = tid >> 1, hf = tid & 1;
  f32x16 acc[4];
#pragma unroll
  for (int i = 0; i < 4; ++i)
#pragma unroll
    for (int j = 0; j < 16; ++j) acc[i][j] = 0.f;

  for (int k0 = 0; k0 < 256; k0 += 64) {
    __syncthreads();
    {
      const unsigned short* sa = xbf + (size_t)(bm + row) * 256 + k0 + hf * 32;
      const unsigned short* sb = W + (size_t)row * 256 + k0 + hf * 32;
#pragma unroll
      for (int i = 0; i < 4; ++i) {
        *(u16x8*)&As[row][hf * 32 + i * 8] = *(const u16x8*)(sa + i * 8);
        *(u16x8*)&Bs[row][hf * 32 + i * 8] = *(const u16x8*)(sb + i * 8);
      }
    }
    __syncthreads();
#pragma unroll
    for (int ks = 0; ks < 4; ++ks) {
      bf8 af = *(const bf8*)&As[w * 32 + lo][ks * 16 + g * 8];
#pragma unroll
      for (int n2 = 0; n2 < 4; ++n2) {
        bf8 bF = *(const bf8*)&Bs[n2 * 32 + lo][ks * 16 + g * 8];
        acc[n2] = __builtin_amdgcn_mfma_f32_32x32x16_bf16(af, bF, acc[n2], 0, 0, 0);
      }
    }
  }
#pragma unroll
  for (int n2 = 0; n2 < 4; ++n2) {
    int col = n2 * 32 + lo;
    float bv = bias[col];
#pragma unroll
    for (int q = 0; q < 4; ++q)
#pragma unroll
      for (int j = 0; j < 4; ++j) {
        size_t r = (size_t)(bm + w * 32 + j + q * 8 + g * 4);
        out[r * 128 + col] = f2bf(acc[n2][q * 4 + j] + bv);
      }
  }
}

// ---------- pool (w2 max) -> Pp row-major bf16, Gt transposed bf16 ----------
__global__ __launch_bounds__(256) void k_pool(
    const unsigned short* __restrict__ Gf, const unsigned short* __restrict__ Pf,
    unsigned short* __restrict__ Pp, unsigned short* __restrict__ Gt)
{
  __shared__ unsigned short pg[32][136];
  const int bid = blockIdx.x;
  const int b = bid >> 6, h = bid & 63;
  const int tid = threadIdx.x;
  {
    const int kv = tid >> 3, q = tid & 7;
    const int c0 = q * 16;
    size_t base = ((size_t)((b * 64 + h) * 64 + kv * 2)) * 128 + c0;
    u16x8 ga0 = *(const u16x8*)&Gf[base], ga1 = *(const u16x8*)&Gf[base + 8];
    u16x8 gb0 = *(const u16x8*)&Gf[base + 128], gb1 = *(const u16x8*)&Gf[base + 136];
    u16x8 pa0 = *(const u16x8*)&Pf[base], pa1 = *(const u16x8*)&Pf[base + 8];
    u16x8 pb0 = *(const u16x8*)&Pf[base + 128], pb1 = *(const u16x8*)&Pf[base + 136];
    u16x8 rg0, rg1, rp0, rp1;
#pragma unroll
    for (int j = 0; j < 8; ++j) {
      rg0[j] = (bf2f(ga0[j]) > bf2f(gb0[j])) ? ga0[j] : gb0[j];
      rg1[j] = (bf2f(ga1[j]) > bf2f(gb1[j])) ? ga1[j] : gb1[j];
      rp0[j] = (bf2f(pa0[j]) > bf2f(pb0[j])) ? pa0[j] : pb0[j];
      rp1[j] = (bf2f(pa1[j]) > bf2f(pb1[j])) ? pa1[j] : pb1[j];
    }
    size_t pdst = ((size_t)(b * 2048 + h * 32 + kv)) * 128 + c0;
    *(u16x8*)&Pp[pdst] = rp0;
    *(u16x8*)&Pp[pdst + 8] = rp1;
    *(u16x8*)&pg[kv][c0] = rg0;
    *(u16x8*)&pg[kv][c0 + 8] = rg1;
  }
  __syncthreads();
  {
    const int c = tid >> 1, hf = tid & 1;
    u16x8 o0, o1;
#pragma unroll
    for (int j = 0; j < 8; ++j) {
      o0[j] = pg[hf * 16 + j][c];
      o1[j] = pg[hf * 16 + 8 + j][c];
    }
    size_t dst = ((size_t)(b * 128 + c)) * 2048 + h * 32 + hf * 16;
    *(u16x8*)&Gt[dst] = o0;
    *(u16x8*)&Gt[dst + 8] = o1;
  }
}

// ---------- MFMA flash attention (swapped QK^T; P in registers) ----------
__global__ __launch_bounds__(128) void k_attn(
    const unsigned short* __restrict__ T, const unsigned short* __restrict__ Pp,
    const unsigned short* __restrict__ Gt, float* __restrict__ Y)
{
  __shared__ unsigned short ph[64][136];   // phi tile [kv][ch]
  __shared__ unsigned short vt[128][72];   // V^T tile [ch][kv]
  const int bid = blockIdx.x;
  const int b = bid & 7, qt = bid >> 3;    // batch pinned to XCD
  const int tid = threadIdx.x;
  const int w = tid >> 6, l = tid & 63;
  const int lo = l & 31, g = l >> 5;
  const int qr0 = qt * 64;

  const unsigned short* Tq = T + ((size_t)(b * 4096 + qr0 + w * 32 + lo)) * 128 + g * 8;
  bf8 qf[8];
#pragma unroll
  for (int ks = 0; ks < 8; ++ks) qf[ks] = *(const bf8*)(Tq + ks * 16);

  f32x16 oacc[4];
#pragma unroll
  for (int i = 0; i < 4; ++i)
#pragma unroll
    for (int j = 0; j < 16; ++j) oacc[i][j] = 0.f;
  float mrun = -3.0e38f, lrun = 0.f;

  const unsigned short* Pb = Pp + (size_t)b * 2048 * 128;
  const unsigned short* Gb = Gt + (size_t)b * 128 * 2048;
  const int skv = tid >> 1, shf = tid & 1;

  for (int t0 = 0; t0 < 2048; t0 += 64) {
    __syncthreads();
    {
      const unsigned short* sp = Pb + (size_t)(t0 + skv) * 128 + shf * 64;
#pragma unroll
      for (int i = 0; i < 8; ++i)
        *(u16x8*)&ph[skv][shf * 64 + i * 8] = *(const u16x8*)(sp + i * 8);
      const unsigned short* sv = Gb + (size_t)tid * 2048 + t0;
#pragma unroll
      for (int i = 0; i < 8; ++i)
        *(u16x8*)&vt[tid][i * 8] = *(const u16x8*)(sv + i * 8);
    }
    __syncthreads();

    // S^T = phi_tile x Q^T  (D col = q-row -> lane-local softmax)
    f32x16 s0, s1;
#pragma unroll
    for (int j = 0; j < 16; ++j) { s0[j] = 0.f; s1[j] = 0.f; }
#pragma unroll
    for (int ks = 0; ks < 8; ++ks) {
      bf8 a0 = *(const bf8*)&ph[lo][ks * 16 + g * 8];
      bf8 a1 = *(const bf8*)&ph[32 + lo][ks * 16 + g * 8];
      s0 = __builtin_amdgcn_mfma_f32_32x32x16_bf16(a0, qf[ks], s0, 0, 0, 0);
      s1 = __builtin_amdgcn_mfma_f32_32x32x16_bf16(a1, qf[ks], s1, 0, 0, 0);
    }

    // online softmax (per-lane row state; partner lane has other kv half)
    float tmx = s0[0];
#pragma unroll
    for (int r = 1; r < 16; ++r) tmx = fmaxf(tmx, s0[r]);
#pragma unroll
    for (int r = 0; r < 16; ++r) tmx = fmaxf(tmx, s1[r]);
    tmx = fmaxf(tmx, __shfl_xor(tmx, 32));
    float mnew = fmaxf(mrun, tmx);
    float al = __expf(mrun - mnew);
    float lsum = 0.f;
#pragma unroll
    for (int r = 0; r < 16; ++r) { s0[r] = __expf(s0[r] - mnew); lsum += s0[r]; }
#pragma unroll
    for (int r = 0; r < 16; ++r) { s1[r] = __expf(s1[r] - mnew); lsum += s1[r]; }
    lsum += __shfl_xor(lsum, 32);
    lrun = lrun * al + lsum;
    mrun = mnew;
#pragma unroll
    for (int n2 = 0; n2 < 4; ++n2)
#pragma unroll
      for (int r = 0; r < 16; ++r) oacc[n2][r] *= al;

    // PV: O^T = V^T x P^T ; P-frags assembled in-register + one lane-32 swap
#pragma unroll
    for (int ks2 = 0; ks2 < 4; ++ks2) {
      const f32x16& pm = (ks2 < 2) ? s0 : s1;
      const int base = 8 * (ks2 & 1);
      unsigned uA0 = pk2(pm[base + 0], pm[base + 1]);
      unsigned uA1 = pk2(pm[base + 2], pm[base + 3]);
      unsigned uB0 = pk2(pm[base + 4], pm[base + 5]);
      unsigned uB1 = pk2(pm[base + 6], pm[base + 7]);
      unsigned sw0 = g ? uA0 : uB0;
      unsigned sw1 = g ? uA1 : uB1;
      unsigned r0 = (unsigned)__shfl_xor((int)sw0, 32);
      unsigned r1 = (unsigned)__shfl_xor((int)sw1, 32);
      union { bf8 v; unsigned u[4]; } pf;
      if (g == 0) { pf.u[0] = uA0; pf.u[1] = uA1; pf.u[2] = r0; pf.u[3] = r1; }
      else        { pf.u[0] = r0;  pf.u[1] = r1;  pf.u[2] = uB0; pf.u[3] = uB1; }
#pragma unroll
      for (int n2 = 0; n2 < 4; ++n2) {
        bf8 vf = *(const bf8*)&vt[n2 * 32 + lo][ks2 * 16 + g * 8];
        oacc[n2] = __builtin_amdgcn_mfma_f32_32x32x16_bf16(vf, pf.v, oacc[n2], 0, 0, 0);
      }
    }
  }

  float inv = 1.f / lrun;
  size_t rowb = ((size_t)(b * 4096 + qr0 + w * 32 + lo)) * 128;
#pragma unroll
  for (int n2 = 0; n2 < 4; ++n2)
#pragma unroll
    for (int q = 0; q < 4; ++q) {
      float4 o = {oacc[n2][q * 4 + 0] * inv, oacc[n2][q * 4 + 1] * inv,
                  oacc[n2][q * 4 + 2] * inv, oacc[n2][q * 4 + 3] * inv};
      *(float4*)&Y[rowb + n2 * 32 + q * 8 + g * 4] = o;
    }
}

// ---------- final: out = (elu(bn2(Y)) @ Wz + bz)*sita + inp ----------
__global__ __launch_bounds__(256) void k_gemm_z(
    const float* __restrict__ Yb, const unsigned short* __restrict__ Wzt,
    const float* __restrict__ bz, const float* __restrict__ bn2s,
    const float* __restrict__ bn2h, const float* __restrict__ inp,
    const float* __restrict__ sita, float* __restrict__ out)
{
  __shared__ unsigned short As[128][72];
  __shared__ unsigned short Bs[128][72];
  const int bm = blockIdx.x * 128, n0 = blockIdx.y * 128;
  const int tid = threadIdx.x;
  const int l = tid & 63, w = tid >> 6, lo = l & 31, g = l >> 5;
  const int row = tid >> 1, hf = tid & 1;
  f32x16 acc[4];
#pragma unroll
  for (int i = 0; i < 4; ++i)
#pragma unroll
    for (int j = 0; j < 16; ++j) acc[i][j] = 0.f;

  for (int k0 = 0; k0 < 128; k0 += 64) {
    __syncthreads();
    {
      const float* sy = Yb + (size_t)(bm + row) * 128 + k0 + hf * 32;
      unsigned short tmp[32];
#pragma unroll
      for (int i = 0; i < 8; ++i) {
        float4 v = *(const float4*)(sy + i * 4);
        int ch = k0 + hf * 32 + i * 4;
        tmp[i * 4 + 0] = f2bf(eluf(v.x * bn2s[ch + 0] + bn2h[ch + 0]));
        tmp[i * 4 + 1] = f2bf(eluf(v.y * bn2s[ch + 1] + bn2h[ch + 1]));
        tmp[i * 4 + 2] = f2bf(eluf(v.z * bn2s[ch + 2] + bn2h[ch + 2]));
        tmp[i * 4 + 3] = f2bf(eluf(v.w * bn2s[ch + 3] + bn2h[ch + 3]));
      }
#pragma unroll
      for (int i = 0; i < 4; ++i)
        *(u16x8*)&As[row][hf * 32 + i * 8] = *(u16x8*)&tmp[i * 8];
      const unsigned short* sb = Wzt + (size_t)(n0 + row) * 128 + k0 + hf * 32;
#pragma unroll
      for (int i = 0; i < 4; ++i)
        *(u16x8*)&Bs[row][hf * 32 + i * 8] = *(const u16x8*)(sb + i * 8);
    }
    __syncthreads();
#pragma unroll
    for (int ks = 0; ks < 4; ++ks) {
      bf8 af = *(const bf8*)&As[w * 32 + lo][ks * 16 + g * 8];
#pragma unroll
      for (int n2 = 0; n2 < 4; ++n2) {
        bf8 bF = *(const bf8*)&Bs[n2 * 32 + lo][ks * 16 + g * 8];
        acc[n2] = __builtin_amdgcn_mfma_f32_32x32x16_bf16(af, bF, acc[n2], 0, 0, 0);
      }
    }
  }
  float st = sita[0];
#pragma unroll
  for (int n2 = 0; n2 < 4; ++n2) {
    int col = n0 + n2 * 32 + lo;
    float bv = bz[col];
#pragma unroll
    for (int q = 0; q < 4; ++q)
#pragma unroll
      for (int j = 0; j < 4; ++j) {
        size_t r = (size_t)(bm + w * 32 + j + q * 8 + g * 4);
        out[r * 256 + col] = (acc[n2][q * 4 + j] + bv) * st + inp[r * 256 + col];
      }
  }
}

extern "C" void kernel_launch(void* const* d_in, const int* in_sizes, int n_in,
                              void* d_out, int out_size, void* d_ws, size_t ws_size,
                              hipStream_t stream) {
  const float* inp   = (const float*)d_in[0];
  const float* bn1_g = (const float*)d_in[1];
  const float* bn1_b = (const float*)d_in[2];
  const float* bn1_m = (const float*)d_in[3];
  const float* bn1_v = (const float*)d_in[4];
  const float* bn2_g = (const float*)d_in[5];
  const float* bn2_b = (const float*)d_in[6];
  const float* bn2_m = (const float*)d_in[7];
  const float* bn2_v = (const float*)d_in[8];
  const float* W_g   = (const float*)d_in[9];
  const float* b_g   = (const float*)d_in[10];
  const float* W_th  = (const float*)d_in[11];
  const float* b_th  = (const float*)d_in[12];
  const float* W_ph  = (const float*)d_in[13];
  const float* b_ph  = (const float*)d_in[14];
  const float* W_z   = (const float*)d_in[15];
  const float* b_z   = (const float*)d_in[16];
  const float* sita  = (const float*)d_in[17];
  float* out = (float*)d_out;

  float* ws_f = (float*)d_ws;
  float* Y    = ws_f;                         // 4194304 f32
  float* bn2s = Y + 4194304;                  // 128
  float* bn2h = bn2s + 128;                   // 128
  unsigned short* xbf = (unsigned short*)(bn2h + 128);
  unsigned short* Tb  = xbf + 8388608;
  unsigned short* Gf  = Tb + 4194304;
  unsigned short* Pf  = Gf + 4194304;
  unsigned short* Pp  = Pf + 4194304;
  unsigned short* Gt  = Pp + 2097152;
  unsigned short* Wt3 = Gt + 2097152;
  unsigned short* Wzt = Wt3 + 98304;

  k_prepw<<<dim3(512), dim3(256), 0, stream>>>(W_th, W_g, W_ph, W_z,
                                               bn2_g, bn2_b, bn2_m, bn2_v,
                                               Wt3, Wzt, bn2s, bn2h);
  k_bn1<<<dim3(4096), dim3(256), 0, stream>>>(inp, bn1_g, bn1_b, bn1_m, bn1_v, xbf);
  k_gemm3<<<dim3(256, 3), dim3(256), 0, stream>>>(xbf, Wt3, b_th, b_g, b_ph, Tb, Gf, Pf);
  k_pool<<<dim3(512), dim3(256), 0, stream>>>(Gf, Pf, Pp, Gt);
  k_attn<<<dim3(512), dim3(128), 0, stream>>>(Tb, Pp, Gt, Y);
  k_gemm_z<<<dim3(256, 2), dim3(256), 0, stream>>>(Y, Wzt, b_z, bn2s, bn2h, inp, sita, out);
}

// Round 3
// 289.828 us; speedup vs baseline: 4.5344x; 1.2034x over previous
//
#include <hip/hip_runtime.h>
#include <math.h>

#define BNEPS 1e-3f

typedef __attribute__((ext_vector_type(8))) short bf8;
typedef __attribute__((ext_vector_type(8))) unsigned short u16x8;
typedef __attribute__((ext_vector_type(16))) float f32x16;

__device__ __forceinline__ unsigned short f2bf(float x) {
  unsigned u = __builtin_bit_cast(unsigned, x);
  unsigned r = (u + 0x7fffu + ((u >> 16) & 1u)) >> 16;
  return (unsigned short)r;
}
__device__ __forceinline__ float bf2f(unsigned short h) {
  return __builtin_bit_cast(float, ((unsigned)h) << 16);
}
__device__ __forceinline__ float eluf(float v) { return v > 0.f ? v : expm1f(v); }
__device__ __forceinline__ unsigned cvtpk(float a, float b) {
  unsigned r;
  asm("v_cvt_pk_bf16_f32 %0, %1, %2" : "=v"(r) : "v"(a), "v"(b));
  return r;  // lo = bf16(a), hi = bf16(b)
}

// ---------- prep: transpose+cast weights to bf16 [N][K]; bn2 scale/shift ----------
__global__ __launch_bounds__(256) void k_prepw(
    const float* __restrict__ Wth, const float* __restrict__ Wg,
    const float* __restrict__ Wph, const float* __restrict__ Wz,
    const float* __restrict__ g2, const float* __restrict__ be2,
    const float* __restrict__ mu2, const float* __restrict__ v2,
    unsigned short* __restrict__ Wt3, unsigned short* __restrict__ Wzt,
    float* __restrict__ bn2s, float* __restrict__ bn2h)
{
  int id = blockIdx.x * 256 + threadIdx.x;
  if (id < 98304) {
    int w = id >> 15, rem = id & 32767;
    int n = rem >> 8, k = rem & 255;
    const float* W = (w == 0) ? Wth : (w == 1) ? Wg : Wph;
    Wt3[id] = f2bf(W[(size_t)k * 128 + n]);
  } else {
    int rem = id - 98304;
    int n = rem >> 7, k = rem & 127;
    Wzt[rem] = f2bf(Wz[(size_t)k * 256 + n]);
  }
  if (id < 128) {
    float s = g2[id] * rsqrtf(v2[id] + BNEPS);
    bn2s[id] = s;
    bn2h[id] = be2[id] - mu2[id] * s;
  }
}

// ---------- bn1 + elu -> bf16 x ----------
__global__ __launch_bounds__(256) void k_bn1(
    const float* __restrict__ in, const float* __restrict__ gm,
    const float* __restrict__ bt, const float* __restrict__ mu,
    const float* __restrict__ vr, unsigned short* __restrict__ x)
{
  int i = blockIdx.x * 256 + threadIdx.x;  // 8 elems each
  const float4* p = (const float4*)(in + (size_t)i * 8);
  float4 a = p[0], c = p[1];
  int c0 = (i * 8) & 255;
  float vals[8] = {a.x, a.y, a.z, a.w, c.x, c.y, c.z, c.w};
  u16x8 o;
#pragma unroll
  for (int j = 0; j < 8; ++j) {
    int ch = c0 + j;
    float s = gm[ch] * rsqrtf(vr[ch] + BNEPS);
    o[j] = f2bf(eluf((vals[j] - mu[ch]) * s + bt[ch]));
  }
  *(u16x8*)(x + (size_t)i * 8) = o;
}

// ---------- 3-in-1 MFMA GEMM: out = bf16(x @ W + b), M=32768 K=256 N=128 ----------
__global__ __launch_bounds__(256) void k_gemm3(
    const unsigned short* __restrict__ xbf, const unsigned short* __restrict__ Wt3,
    const float* __restrict__ bth, const float* __restrict__ bg,
    const float* __restrict__ bph, unsigned short* __restrict__ Tb,
    unsigned short* __restrict__ Gf, unsigned short* __restrict__ Pf)
{
  __shared__ unsigned short As[128][72];
  __shared__ unsigned short Bs[128][72];
  const int bm = blockIdx.x * 128;
  const int sel = blockIdx.y;
  const unsigned short* W = Wt3 + (size_t)sel * 32768;
  const float* bias = (sel == 0) ? bth : (sel == 1) ? bg : bph;
  unsigned short* out = (sel == 0) ? Tb : (sel == 1) ? Gf : Pf;
  const int tid = threadIdx.x;
  const int l = tid & 63, w = tid >> 6;
  const int lo = l & 31, g = l >> 5;
  const int row = tid >> 1, hf = tid & 1;
  f32x16 acc[4];
#pragma unroll
  for (int i = 0; i < 4; ++i)
#pragma unroll
    for (int j = 0; j < 16; ++j) acc[i][j] = 0.f;

  for (int k0 = 0; k0 < 256; k0 += 64) {
    __syncthreads();
    {
      const unsigned short* sa = xbf + (size_t)(bm + row) * 256 + k0 + hf * 32;
      const unsigned short* sb = W + (size_t)row * 256 + k0 + hf * 32;
#pragma unroll
      for (int i = 0; i < 4; ++i) {
        *(u16x8*)&As[row][hf * 32 + i * 8] = *(const u16x8*)(sa + i * 8);
        *(u16x8*)&Bs[row][hf * 32 + i * 8] = *(const u16x8*)(sb + i * 8);
      }
    }
    __syncthreads();
#pragma unroll
    for (int ks = 0; ks < 4; ++ks) {
      bf8 af = *(const bf8*)&As[w * 32 + lo][ks * 16 + g * 8];
#pragma unroll
      for (int n2 = 0; n2 < 4; ++n2) {
        bf8 bF = *(const bf8*)&Bs[n2 * 32 + lo][ks * 16 + g * 8];
        acc[n2] = __builtin_amdgcn_mfma_f32_32x32x16_bf16(af, bF, acc[n2], 0, 0, 0);
      }
    }
  }
#pragma unroll
  for (int n2 = 0; n2 < 4; ++n2) {
    int col = n2 * 32 + lo;
    float bv = bias[col];
#pragma unroll
    for (int q = 0; q < 4; ++q)
#pragma unroll
      for (int j = 0; j < 4; ++j) {
        size_t r = (size_t)(bm + w * 32 + j + q * 8 + g * 4);
        out[r * 128 + col] = f2bf(acc[n2][q * 4 + j] + bv);
      }
  }
}

// ---------- pool (w2 max) -> Pp row-major bf16, Gt transposed bf16 ----------
__global__ __launch_bounds__(256) void k_pool(
    const unsigned short* __restrict__ Gf, const unsigned short* __restrict__ Pf,
    unsigned short* __restrict__ Pp, unsigned short* __restrict__ Gt)
{
  __shared__ unsigned short pg[32][136];
  const int bid = blockIdx.x;
  const int b = bid >> 6, h = bid & 63;
  const int tid = threadIdx.x;
  {
    const int kv = tid >> 3, q = tid & 7;
    const int c0 = q * 16;
    size_t base = ((size_t)((b * 64 + h) * 64 + kv * 2)) * 128 + c0;
    u16x8 ga0 = *(const u16x8*)&Gf[base], ga1 = *(const u16x8*)&Gf[base + 8];
    u16x8 gb0 = *(const u16x8*)&Gf[base + 128], gb1 = *(const u16x8*)&Gf[base + 136];
    u16x8 pa0 = *(const u16x8*)&Pf[base], pa1 = *(const u16x8*)&Pf[base + 8];
    u16x8 pb0 = *(const u16x8*)&Pf[base + 128], pb1 = *(const u16x8*)&Pf[base + 136];
    u16x8 rg0, rg1, rp0, rp1;
#pragma unroll
    for (int j = 0; j < 8; ++j) {
      rg0[j] = (bf2f(ga0[j]) > bf2f(gb0[j])) ? ga0[j] : gb0[j];
      rg1[j] = (bf2f(ga1[j]) > bf2f(gb1[j])) ? ga1[j] : gb1[j];
      rp0[j] = (bf2f(pa0[j]) > bf2f(pb0[j])) ? pa0[j] : pb0[j];
      rp1[j] = (bf2f(pa1[j]) > bf2f(pb1[j])) ? pa1[j] : pb1[j];
    }
    size_t pdst = ((size_t)(b * 2048 + h * 32 + kv)) * 128 + c0;
    *(u16x8*)&Pp[pdst] = rp0;
    *(u16x8*)&Pp[pdst + 8] = rp1;
    *(u16x8*)&pg[kv][c0] = rg0;
    *(u16x8*)&pg[kv][c0 + 8] = rg1;
  }
  __syncthreads();
  {
    const int c = tid >> 1, hf = tid & 1;
    u16x8 o0, o1;
#pragma unroll
    for (int j = 0; j < 8; ++j) {
      o0[j] = pg[hf * 16 + j][c];
      o1[j] = pg[hf * 16 + 8 + j][c];
    }
    size_t dst = ((size_t)(b * 128 + c)) * 2048 + h * 32 + hf * 16;
    *(u16x8*)&Gt[dst] = o0;
    *(u16x8*)&Gt[dst + 8] = o1;
  }
}

// ---------- MFMA flash attention, KV-split x2, no-max softmax, reg prefetch ----------
// grid 1024: bid = ((half*64 + qt)*8) + b ; writes unnormalized O_part + l_part.
__global__ __launch_bounds__(128, 2) void k_attn(
    const unsigned short* __restrict__ T, const unsigned short* __restrict__ Pp,
    const unsigned short* __restrict__ Gt, float* __restrict__ Opart,
    float* __restrict__ lpart)
{
  __shared__ unsigned short ph[64][136];   // phi tile [kv][ch]
  __shared__ unsigned short vt[128][72];   // V^T tile [ch][kv]
  const int bid = blockIdx.x;
  const int b = bid & 7;                   // batch pinned to XCD
  const int rest = bid >> 3;
  const int qt = rest & 63;
  const int half = rest >> 6;
  const int tid = threadIdx.x;
  const int w = tid >> 6, l = tid & 63;
  const int lo = l & 31, g = l >> 5;
  const int qr0 = qt * 64;

  const unsigned short* Tq = T + ((size_t)(b * 4096 + qr0 + w * 32 + lo)) * 128 + g * 8;
  bf8 qf[8];
#pragma unroll
  for (int ks = 0; ks < 8; ++ks) qf[ks] = *(const bf8*)(Tq + ks * 16);

  f32x16 oacc[4];
#pragma unroll
  for (int i = 0; i < 4; ++i)
#pragma unroll
    for (int j = 0; j < 16; ++j) oacc[i][j] = 0.f;
  float lrun = 0.f;

  const unsigned short* Pb = Pp + ((size_t)b * 2048 + half * 1024) * 128;
  const unsigned short* Gb = Gt + (size_t)b * 128 * 2048 + half * 1024;
  const int skv = tid >> 1, shf = tid & 1;

  u16x8 rp[8], rv[8];
  {
    const unsigned short* sp = Pb + (size_t)skv * 128 + shf * 64;
    const unsigned short* sv = Gb + (size_t)tid * 2048;
#pragma unroll
    for (int i = 0; i < 8; ++i) {
      rp[i] = *(const u16x8*)(sp + i * 8);
      rv[i] = *(const u16x8*)(sv + i * 8);
    }
  }

  for (int it = 0; it < 16; ++it) {
    // commit prefetched tile to LDS
#pragma unroll
    for (int i = 0; i < 8; ++i) {
      *(u16x8*)&ph[skv][shf * 64 + i * 8] = rp[i];
      *(u16x8*)&vt[tid][i * 8] = rv[i];
    }
    __syncthreads();
    if (it < 15) {  // issue next tile's loads early (latency hides under MFMA)
      const int t0 = (it + 1) * 64;
      const unsigned short* sp = Pb + (size_t)(t0 + skv) * 128 + shf * 64;
      const unsigned short* sv = Gb + (size_t)tid * 2048 + t0;
#pragma unroll
      for (int i = 0; i < 8; ++i) {
        rp[i] = *(const u16x8*)(sp + i * 8);
        rv[i] = *(const u16x8*)(sv + i * 8);
      }
    }

    // S^T = phi_tile x Q^T  (D col = q-row -> lane-local softmax)
    f32x16 s0, s1;
#pragma unroll
    for (int j = 0; j < 16; ++j) { s0[j] = 0.f; s1[j] = 0.f; }
#pragma unroll
    for (int ks = 0; ks < 8; ++ks) {
      bf8 a0 = *(const bf8*)&ph[lo][ks * 16 + g * 8];
      bf8 a1 = *(const bf8*)&ph[32 + lo][ks * 16 + g * 8];
      s0 = __builtin_amdgcn_mfma_f32_32x32x16_bf16(a0, qf[ks], s0, 0, 0, 0);
      s1 = __builtin_amdgcn_mfma_f32_32x32x16_bf16(a1, qf[ks], s1, 0, 0, 0);
    }

    // no-max softmax: P = exp(S); per-lane partial l (partner added at end)
#pragma unroll
    for (int r = 0; r < 16; ++r) { s0[r] = __expf(s0[r]); lrun += s0[r]; }
#pragma unroll
    for (int r = 0; r < 16; ++r) { s1[r] = __expf(s1[r]); lrun += s1[r]; }

    // PV: O^T = V^T x P^T ; P-frags assembled in-register + one lane-32 swap
#pragma unroll
    for (int ks2 = 0; ks2 < 4; ++ks2) {
      const f32x16& pm = (ks2 < 2) ? s0 : s1;
      const int base = 8 * (ks2 & 1);
      unsigned uA0 = cvtpk(pm[base + 0], pm[base + 1]);
      unsigned uA1 = cvtpk(pm[base + 2], pm[base + 3]);
      unsigned uB0 = cvtpk(pm[base + 4], pm[base + 5]);
      unsigned uB1 = cvtpk(pm[base + 6], pm[base + 7]);
      unsigned sw0 = g ? uA0 : uB0;
      unsigned sw1 = g ? uA1 : uB1;
      unsigned r0 = (unsigned)__shfl_xor((int)sw0, 32);
      unsigned r1 = (unsigned)__shfl_xor((int)sw1, 32);
      union { bf8 v; unsigned u[4]; } pf;
      if (g == 0) { pf.u[0] = uA0; pf.u[1] = uA1; pf.u[2] = r0; pf.u[3] = r1; }
      else        { pf.u[0] = r0;  pf.u[1] = r1;  pf.u[2] = uB0; pf.u[3] = uB1; }
#pragma unroll
      for (int n2 = 0; n2 < 4; ++n2) {
        bf8 vf = *(const bf8*)&vt[n2 * 32 + lo][ks2 * 16 + g * 8];
        oacc[n2] = __builtin_amdgcn_mfma_f32_32x32x16_bf16(vf, pf.v, oacc[n2], 0, 0, 0);
      }
    }
    __syncthreads();
  }

  lrun += __shfl_xor(lrun, 32);  // partner lane holds other half of each row-sum
  const int qrow = qr0 + w * 32 + lo;
  size_t rowb = ((size_t)half * 4194304) + ((size_t)(b * 4096 + qrow)) * 128;
#pragma unroll
  for (int n2 = 0; n2 < 4; ++n2)
#pragma unroll
    for (int q = 0; q < 4; ++q) {
      float4 o = {oacc[n2][q * 4 + 0], oacc[n2][q * 4 + 1],
                  oacc[n2][q * 4 + 2], oacc[n2][q * 4 + 3]};
      *(float4*)&Opart[rowb + n2 * 32 + q * 8 + g * 4] = o;
    }
  if (g == 0) lpart[(size_t)half * 32768 + b * 4096 + qrow] = lrun;
}

// ---------- final: out = (elu(bn2((O0+O1)/l)) @ Wz + bz)*sita + inp ----------
__global__ __launch_bounds__(256) void k_gemm_z(
    const float* __restrict__ O0, const float* __restrict__ O1,
    const float* __restrict__ l0, const float* __restrict__ l1,
    const unsigned short* __restrict__ Wzt,
    const float* __restrict__ bz, const float* __restrict__ bn2s,
    const float* __restrict__ bn2h, const float* __restrict__ inp,
    const float* __restrict__ sita, float* __restrict__ out)
{
  __shared__ unsigned short As[128][72];
  __shared__ unsigned short Bs[128][72];
  const int bm = blockIdx.x * 128, n0 = blockIdx.y * 128;
  const int tid = threadIdx.x;
  const int l = tid & 63, w = tid >> 6, lo = l & 31, g = l >> 5;
  const int row = tid >> 1, hf = tid & 1;
  const size_t grow = (size_t)(bm + row);
  const float inv = 1.f / (l0[grow] + l1[grow]);
  f32x16 acc[4];
#pragma unroll
  for (int i = 0; i < 4; ++i)
#pragma unroll
    for (int j = 0; j < 16; ++j) acc[i][j] = 0.f;

  for (int k0 = 0; k0 < 128; k0 += 64) {
    __syncthreads();
    {
      const float* s0p = O0 + grow * 128 + k0 + hf * 32;
      const float* s1p = O1 + grow * 128 + k0 + hf * 32;
      unsigned short tmp[32];
#pragma unroll
      for (int i = 0; i < 8; ++i) {
        float4 va = *(const float4*)(s0p + i * 4);
        float4 vb = *(const float4*)(s1p + i * 4);
        int ch = k0 + hf * 32 + i * 4;
        float y0 = (va.x + vb.x) * inv, y1 = (va.y + vb.y) * inv;
        float y2 = (va.z + vb.z) * inv, y3 = (va.w + vb.w) * inv;
        tmp[i * 4 + 0] = f2bf(eluf(y0 * bn2s[ch + 0] + bn2h[ch + 0]));
        tmp[i * 4 + 1] = f2bf(eluf(y1 * bn2s[ch + 1] + bn2h[ch + 1]));
        tmp[i * 4 + 2] = f2bf(eluf(y2 * bn2s[ch + 2] + bn2h[ch + 2]));
        tmp[i * 4 + 3] = f2bf(eluf(y3 * bn2s[ch + 3] + bn2h[ch + 3]));
      }
#pragma unroll
      for (int i = 0; i < 4; ++i)
        *(u16x8*)&As[row][hf * 32 + i * 8] = *(u16x8*)&tmp[i * 8];
      const unsigned short* sb = Wzt + (size_t)(n0 + row) * 128 + k0 + hf * 32;
#pragma unroll
      for (int i = 0; i < 4; ++i)
        *(u16x8*)&Bs[row][hf * 32 + i * 8] = *(const u16x8*)(sb + i * 8);
    }
    __syncthreads();
#pragma unroll
    for (int ks = 0; ks < 4; ++ks) {
      bf8 af = *(const bf8*)&As[w * 32 + lo][ks * 16 + g * 8];
#pragma unroll
      for (int n2 = 0; n2 < 4; ++n2) {
        bf8 bF = *(const bf8*)&Bs[n2 * 32 + lo][ks * 16 + g * 8];
        acc[n2] = __builtin_amdgcn_mfma_f32_32x32x16_bf16(af, bF, acc[n2], 0, 0, 0);
      }
    }
  }
  float st = sita[0];
#pragma unroll
  for (int n2 = 0; n2 < 4; ++n2) {
    int col = n0 + n2 * 32 + lo;
    float bv = bz[col];
#pragma unroll
    for (int q = 0; q < 4; ++q)
#pragma unroll
      for (int j = 0; j < 4; ++j) {
        size_t r = (size_t)(bm + w * 32 + j + q * 8 + g * 4);
        out[r * 256 + col] = (acc[n2][q * 4 + j] + bv) * st + inp[r * 256 + col];
      }
  }
}

extern "C" void kernel_launch(void* const* d_in, const int* in_sizes, int n_in,
                              void* d_out, int out_size, void* d_ws, size_t ws_size,
                              hipStream_t stream) {
  const float* inp   = (const float*)d_in[0];
  const float* bn1_g = (const float*)d_in[1];
  const float* bn1_b = (const float*)d_in[2];
  const float* bn1_m = (const float*)d_in[3];
  const float* bn1_v = (const float*)d_in[4];
  const float* bn2_g = (const float*)d_in[5];
  const float* bn2_b = (const float*)d_in[6];
  const float* bn2_m = (const float*)d_in[7];
  const float* bn2_v = (const float*)d_in[8];
  const float* W_g   = (const float*)d_in[9];
  const float* b_g   = (const float*)d_in[10];
  const float* W_th  = (const float*)d_in[11];
  const float* b_th  = (const float*)d_in[12];
  const float* W_ph  = (const float*)d_in[13];
  const float* b_ph  = (const float*)d_in[14];
  const float* W_z   = (const float*)d_in[15];
  const float* b_z   = (const float*)d_in[16];
  const float* sita  = (const float*)d_in[17];
  float* out = (float*)d_out;

  float* ws_f = (float*)d_ws;
  float* O0   = ws_f;                         // 4194304
  float* O1   = O0 + 4194304;                 // 4194304
  float* l0   = O1 + 4194304;                 // 32768
  float* l1   = l0 + 32768;                   // 32768
  float* bn2s = l1 + 32768;                   // 128
  float* bn2h = bn2s + 128;                   // 128
  unsigned short* xbf = (unsigned short*)(bn2h + 128);
  unsigned short* Tb  = xbf + 8388608;
  unsigned short* Gf  = Tb + 4194304;
  unsigned short* Pf  = Gf + 4194304;
  unsigned short* Pp  = Pf + 4194304;
  unsigned short* Gt  = Pp + 2097152;
  unsigned short* Wt3 = Gt + 2097152;
  unsigned short* Wzt = Wt3 + 98304;

  k_prepw<<<dim3(512), dim3(256), 0, stream>>>(W_th, W_g, W_ph, W_z,
                                               bn2_g, bn2_b, bn2_m, bn2_v,
                                               Wt3, Wzt, bn2s, bn2h);
  k_bn1<<<dim3(4096), dim3(256), 0, stream>>>(inp, bn1_g, bn1_b, bn1_m, bn1_v, xbf);
  k_gemm3<<<dim3(256, 3), dim3(256), 0, stream>>>(xbf, Wt3, b_th, b_g, b_ph, Tb, Gf, Pf);
  k_pool<<<dim3(512), dim3(256), 0, stream>>>(Gf, Pf, Pp, Gt);
  k_attn<<<dim3(1024), dim3(128), 0, stream>>>(Tb, Pp, Gt, O0, l0);
  k_gemm_z<<<dim3(256, 2), dim3(256), 0, stream>>>(O0, O1, l0, l1, Wzt, b_z,
                                                   bn2s, bn2h, inp, sita, out);
}

// Round 4
// 251.345 us; speedup vs baseline: 5.2287x; 1.1531x over previous
//
#include <hip/hip_runtime.h>
#include <math.h>

#define BNEPS 1e-3f
#define LOG2E 1.44269504f

typedef __attribute__((ext_vector_type(8))) short bf8;
typedef __attribute__((ext_vector_type(8))) unsigned short u16x8;
typedef __attribute__((ext_vector_type(16))) float f32x16;
typedef __attribute__((ext_vector_type(2))) unsigned u32x2;

__device__ __forceinline__ unsigned short f2bf(float x) {
  unsigned u = __builtin_bit_cast(unsigned, x);
  unsigned r = (u + 0x7fffu + ((u >> 16) & 1u)) >> 16;
  return (unsigned short)r;
}
__device__ __forceinline__ float bf2f(unsigned short h) {
  return __builtin_bit_cast(float, ((unsigned)h) << 16);
}
__device__ __forceinline__ float eluf(float v) { return v > 0.f ? v : expm1f(v); }
__device__ __forceinline__ unsigned cvtpk(float a, float b) {
  unsigned r;
  asm("v_cvt_pk_bf16_f32 %0, %1, %2" : "=v"(r) : "v"(a), "v"(b));
  return r;  // lo = bf16(a), hi = bf16(b)
}
__device__ __forceinline__ float exp2a(float x) {
  float r;
  asm("v_exp_f32 %0, %1" : "=v"(r) : "v"(x));
  return r;  // 2^x
}

#define GLDS(src, dst)                                                          \
  __builtin_amdgcn_global_load_lds(                                             \
      (const __attribute__((address_space(1))) unsigned int*)(src),             \
      (__attribute__((address_space(3))) unsigned int*)(dst), 16, 0, 0)

// ---------- prep: transpose+cast weights to bf16 [N][K]; bn1/bn2 scale/shift ----------
__global__ __launch_bounds__(256) void k_prepw(
    const float* __restrict__ Wth, const float* __restrict__ Wg,
    const float* __restrict__ Wph, const float* __restrict__ Wz,
    const float* __restrict__ g1, const float* __restrict__ b1,
    const float* __restrict__ m1, const float* __restrict__ v1,
    const float* __restrict__ g2, const float* __restrict__ b2,
    const float* __restrict__ m2, const float* __restrict__ v2,
    unsigned short* __restrict__ Wt3, unsigned short* __restrict__ Wzt,
    float* __restrict__ bn1s, float* __restrict__ bn1h,
    float* __restrict__ bn2s, float* __restrict__ bn2h)
{
  int id = blockIdx.x * 256 + threadIdx.x;
  if (id < 98304) {
    int w = id >> 15, rem = id & 32767;
    int n = rem >> 8, k = rem & 255;
    const float* W = (w == 0) ? Wth : (w == 1) ? Wg : Wph;
    Wt3[id] = f2bf(W[(size_t)k * 128 + n]);
  } else {
    int rem = id - 98304;
    int n = rem >> 7, k = rem & 127;
    Wzt[rem] = f2bf(Wz[(size_t)k * 256 + n]);
  }
  if (id < 256) { float s = g1[id] * rsqrtf(v1[id] + BNEPS); bn1s[id] = s; bn1h[id] = b1[id] - m1[id] * s; }
  if (id < 128) { float s = g2[id] * rsqrtf(v2[id] + BNEPS); bn2s[id] = s; bn2h[id] = b2[id] - m2[id] * s; }
}

// ---------- GEMM3: x=elu(bn1(inp)) fused in A-staging; M=32768 K=256 N=128 ----------
// sel0 -> Tb rows (pre-scaled by log2e); sel1 -> pooled V^T in Gt2 chunk layout;
// sel2 -> pooled phi in Pp2 chunk layout.
__global__ __launch_bounds__(256) void k_gemm3(
    const float* __restrict__ inp, const float* __restrict__ bn1s,
    const float* __restrict__ bn1h, const unsigned short* __restrict__ Wt3,
    const float* __restrict__ bth, const float* __restrict__ bg,
    const float* __restrict__ bph, unsigned short* __restrict__ Tb,
    unsigned short* __restrict__ Gt2, unsigned short* __restrict__ Pp2)
{
  __shared__ unsigned short As[128][72];
  __shared__ unsigned short Bs[128][72];
  const int bm = blockIdx.x * 128;
  const int sel = blockIdx.y;
  const unsigned short* W = Wt3 + (size_t)sel * 32768;
  const float* bias = (sel == 0) ? bth : (sel == 1) ? bg : bph;
  const int tid = threadIdx.x;
  const int l = tid & 63, w = tid >> 6;
  const int lo = l & 31, g = l >> 5;
  const int row = tid >> 1, hf = tid & 1;
  f32x16 acc[4];
#pragma unroll
  for (int i = 0; i < 4; ++i)
#pragma unroll
    for (int j = 0; j < 16; ++j) acc[i][j] = 0.f;

  for (int k0 = 0; k0 < 256; k0 += 64) {
    __syncthreads();
    {
      const float* sa = inp + (size_t)(bm + row) * 256 + k0 + hf * 32;
      unsigned short tmp[32];
#pragma unroll
      for (int i = 0; i < 8; ++i) {
        float4 v = *(const float4*)(sa + i * 4);
        int ch = k0 + hf * 32 + i * 4;
        tmp[i * 4 + 0] = f2bf(eluf(v.x * bn1s[ch + 0] + bn1h[ch + 0]));
        tmp[i * 4 + 1] = f2bf(eluf(v.y * bn1s[ch + 1] + bn1h[ch + 1]));
        tmp[i * 4 + 2] = f2bf(eluf(v.z * bn1s[ch + 2] + bn1h[ch + 2]));
        tmp[i * 4 + 3] = f2bf(eluf(v.w * bn1s[ch + 3] + bn1h[ch + 3]));
      }
#pragma unroll
      for (int i = 0; i < 4; ++i)
        *(u16x8*)&As[row][hf * 32 + i * 8] = *(u16x8*)&tmp[i * 8];
      const unsigned short* sb = W + (size_t)row * 256 + k0 + hf * 32;
#pragma unroll
      for (int i = 0; i < 4; ++i)
        *(u16x8*)&Bs[row][hf * 32 + i * 8] = *(const u16x8*)(sb + i * 8);
    }
    __syncthreads();
#pragma unroll
    for (int ks = 0; ks < 4; ++ks) {
      bf8 af = *(const bf8*)&As[w * 32 + lo][ks * 16 + g * 8];
#pragma unroll
      for (int n2 = 0; n2 < 4; ++n2) {
        bf8 bF = *(const bf8*)&Bs[n2 * 32 + lo][ks * 16 + g * 8];
        acc[n2] = __builtin_amdgcn_mfma_f32_32x32x16_bf16(af, bF, acc[n2], 0, 0, 0);
      }
    }
  }

  if (sel == 0) {
#pragma unroll
    for (int n2 = 0; n2 < 4; ++n2) {
      int col = n2 * 32 + lo;
      float bv = bias[col];
#pragma unroll
      for (int q = 0; q < 4; ++q)
#pragma unroll
        for (int j = 0; j < 4; ++j) {
          size_t r = (size_t)(bm + w * 32 + j + q * 8 + g * 4);
          Tb[r * 128 + col] = f2bf((acc[n2][q * 4 + j] + bv) * LOG2E);
        }
    }
  } else {
#pragma unroll
    for (int n2 = 0; n2 < 4; ++n2) {
      int col = n2 * 32 + lo;
      float bv = bias[col];
#pragma unroll
      for (int q = 0; q < 4; ++q)
#pragma unroll
        for (int jp = 0; jp < 2; ++jp) {
          int j = jp * 2;
          float v0 = acc[n2][q * 4 + j] + bv;
          float v1 = acc[n2][q * 4 + j + 1] + bv;
          float mx = fmaxf(v0, v1);
          int r = bm + w * 32 + q * 8 + g * 4 + j;   // even global row
          int pr = r >> 1;
          int b = pr >> 11, local = pr & 2047;
          int kb = local >> 5, sub = (local >> 3) & 3, m = local & 7, kv5 = local & 31;
          if (sel == 1)
            Gt2[((((size_t)b * 64 + kb) * 4 + sub) * 128 + col) * 8 + m] = f2bf(mx);
          else
            Pp2[((((size_t)b * 64 + kb) * 16 + (col >> 3)) * 32 + kv5) * 8 + (col & 7)] = f2bf(mx);
        }
    }
  }
}

// ---------- MFMA flash attention: KV-split x4, kv-tile 32, global_load_lds staging ----------
// grid 2048: bid = ((split*64 + qt)*8) + b. Writes bf16 unnormalized O_part + fp32 l_part.
__global__ __launch_bounds__(128, 4) void k_attn(
    const unsigned short* __restrict__ T, const unsigned short* __restrict__ Pp2,
    const unsigned short* __restrict__ Gt2, unsigned short* __restrict__ Opart,
    float* __restrict__ lpart)
{
  __shared__ unsigned short phl[4096];   // [csub=ch>>3][kv 32][8ch]  (512 el / csub)
  __shared__ unsigned short vtl[4096];   // [sub=kv>>3][ch 128][8kv]  (1024 el / sub)
  const int bid = blockIdx.x;
  const int b = bid & 7, qt = (bid >> 3) & 63, sp = bid >> 9;
  const int tid = threadIdx.x;
  const int w = tid >> 6, l = tid & 63;
  const int lo = l & 31, g = l >> 5;
  const int qr0 = qt * 64;

  const unsigned short* Tq = T + ((size_t)(b * 4096 + qr0 + w * 32 + lo)) * 128 + g * 8;
  bf8 qf[8];
#pragma unroll
  for (int ks = 0; ks < 8; ++ks) qf[ks] = *(const bf8*)(Tq + ks * 16);

  f32x16 oacc[4];
#pragma unroll
  for (int i = 0; i < 4; ++i)
#pragma unroll
    for (int j = 0; j < 16; ++j) oacc[i][j] = 0.f;
  float lrun = 0.f;

  const unsigned short* Pc = Pp2 + ((size_t)b * 64 + sp * 16) * 4096;
  const unsigned short* Gc = Gt2 + ((size_t)b * 64 + sp * 16) * 4096;

  for (int it = 0; it < 16; ++it) {
    const unsigned short* ps = Pc + (size_t)it * 4096 + w * 2048 + l * 8;
    const unsigned short* vs = Gc + (size_t)it * 4096 + w * 2048 + l * 8;
#pragma unroll
    for (int j = 0; j < 4; ++j) {
      GLDS(ps + j * 512, &phl[(w * 4 + j) * 512]);
      GLDS(vs + j * 512, &vtl[(w * 4 + j) * 512]);
    }
    __syncthreads();   // drains vmcnt -> LDS tile ready

    // S^T = phi_tile(32kv) x Q^T : lane holds 16 of 32 kv for q-row lo
    f32x16 s0;
#pragma unroll
    for (int j = 0; j < 16; ++j) s0[j] = 0.f;
#pragma unroll
    for (int ks = 0; ks < 8; ++ks) {
      bf8 a0 = *(const bf8*)&phl[(ks * 2 + g) * 256 + lo * 8];
      s0 = __builtin_amdgcn_mfma_f32_32x32x16_bf16(a0, qf[ks], s0, 0, 0, 0);
    }

    // no-max softmax: P = 2^(S') (theta pre-scaled by log2e)
#pragma unroll
    for (int r = 0; r < 16; ++r) { s0[r] = exp2a(s0[r]); lrun += s0[r]; }

    // PV: O^T += V^T x P^T ; half-exchange via v_permlane32_swap (VALU, no LDS)
#pragma unroll
    for (int ks2 = 0; ks2 < 2; ++ks2) {
      const int base = 8 * ks2;
      unsigned uA0 = cvtpk(s0[base + 0], s0[base + 1]);
      unsigned uA1 = cvtpk(s0[base + 2], s0[base + 3]);
      unsigned uB0 = cvtpk(s0[base + 4], s0[base + 5]);
      unsigned uB1 = cvtpk(s0[base + 6], s0[base + 7]);
      unsigned sw0 = g ? uA0 : uB0;
      unsigned sw1 = g ? uA1 : uB1;
      unsigned a0 = sw0, b0 = sw0, a1 = sw1, b1 = sw1;
      asm("v_permlane32_swap_b32 %0, %1" : "+v"(a0), "+v"(b0));
      asm("v_permlane32_swap_b32 %0, %1" : "+v"(a1), "+v"(b1));
      unsigned r0 = g ? a0 : b0;   // partner's sw0
      unsigned r1 = g ? a1 : b1;   // partner's sw1
      union { bf8 v; unsigned u[4]; } pf;
      if (g == 0) { pf.u[0] = uA0; pf.u[1] = uA1; pf.u[2] = r0; pf.u[3] = r1; }
      else        { pf.u[0] = r0;  pf.u[1] = r1;  pf.u[2] = uB0; pf.u[3] = uB1; }
#pragma unroll
      for (int n2 = 0; n2 < 4; ++n2) {
        bf8 vf = *(const bf8*)&vtl[(ks2 * 2 + g) * 1024 + (n2 * 32 + lo) * 8];
        oacc[n2] = __builtin_amdgcn_mfma_f32_32x32x16_bf16(vf, pf.v, oacc[n2], 0, 0, 0);
      }
    }
    __syncthreads();   // all waves done reading before next DMA overwrites
  }

  lrun += __shfl_xor(lrun, 32);  // partner holds other 16 kv of each row-sum
  const int qrow = qr0 + w * 32 + lo;
  unsigned short* Ob = Opart + (size_t)sp * 4194304 + ((size_t)(b * 4096 + qrow)) * 128;
#pragma unroll
  for (int n2 = 0; n2 < 4; ++n2)
#pragma unroll
    for (int q4 = 0; q4 < 4; ++q4) {
      unsigned u0 = cvtpk(oacc[n2][q4 * 4 + 0], oacc[n2][q4 * 4 + 1]);
      unsigned u1 = cvtpk(oacc[n2][q4 * 4 + 2], oacc[n2][q4 * 4 + 3]);
      u32x2 o = {u0, u1};
      *(u32x2*)&Ob[n2 * 32 + q4 * 8 + g * 4] = o;
    }
  if (g == 0) lpart[(size_t)sp * 32768 + b * 4096 + qrow] = lrun;
}

// ---------- final: out = (elu(bn2(sum(Opart)/suml)) @ Wz + bz)*sita + inp ----------
__global__ __launch_bounds__(256) void k_gemm_z(
    const unsigned short* __restrict__ Opart, const float* __restrict__ lp,
    const unsigned short* __restrict__ Wzt,
    const float* __restrict__ bz, const float* __restrict__ bn2s,
    const float* __restrict__ bn2h, const float* __restrict__ inp,
    const float* __restrict__ sita, float* __restrict__ out)
{
  __shared__ unsigned short As[128][72];
  __shared__ unsigned short Bs[128][72];
  const int bm = blockIdx.x * 128, n0 = blockIdx.y * 128;
  const int tid = threadIdx.x;
  const int l = tid & 63, w = tid >> 6, lo = l & 31, g = l >> 5;
  const int row = tid >> 1, hf = tid & 1;
  const size_t grow = (size_t)(bm + row);
  const float inv = 1.f / (lp[grow] + lp[32768 + grow] + lp[65536 + grow] + lp[98304 + grow]);
  f32x16 acc[4];
#pragma unroll
  for (int i = 0; i < 4; ++i)
#pragma unroll
    for (int j = 0; j < 16; ++j) acc[i][j] = 0.f;

  for (int k0 = 0; k0 < 128; k0 += 64) {
    __syncthreads();
    {
      unsigned short tmp[32];
#pragma unroll
      for (int i = 0; i < 4; ++i) {
        size_t off = grow * 128 + k0 + hf * 32 + i * 8;
        u16x8 p0 = *(const u16x8*)&Opart[off];
        u16x8 p1 = *(const u16x8*)&Opart[4194304 + off];
        u16x8 p2 = *(const u16x8*)&Opart[8388608 + off];
        u16x8 p3 = *(const u16x8*)&Opart[12582912 + off];
#pragma unroll
        for (int j = 0; j < 8; ++j) {
          int ch = k0 + hf * 32 + i * 8 + j;
          float y = (bf2f(p0[j]) + bf2f(p1[j]) + bf2f(p2[j]) + bf2f(p3[j])) * inv;
          tmp[i * 8 + j] = f2bf(eluf(y * bn2s[ch] + bn2h[ch]));
        }
      }
#pragma unroll
      for (int i = 0; i < 4; ++i)
        *(u16x8*)&As[row][hf * 32 + i * 8] = *(u16x8*)&tmp[i * 8];
      const unsigned short* sb = Wzt + (size_t)(n0 + row) * 128 + k0 + hf * 32;
#pragma unroll
      for (int i = 0; i < 4; ++i)
        *(u16x8*)&Bs[row][hf * 32 + i * 8] = *(const u16x8*)(sb + i * 8);
    }
    __syncthreads();
#pragma unroll
    for (int ks = 0; ks < 4; ++ks) {
      bf8 af = *(const bf8*)&As[w * 32 + lo][ks * 16 + g * 8];
#pragma unroll
      for (int n2 = 0; n2 < 4; ++n2) {
        bf8 bF = *(const bf8*)&Bs[n2 * 32 + lo][ks * 16 + g * 8];
        acc[n2] = __builtin_amdgcn_mfma_f32_32x32x16_bf16(af, bF, acc[n2], 0, 0, 0);
      }
    }
  }
  float st = sita[0];
#pragma unroll
  for (int n2 = 0; n2 < 4; ++n2) {
    int col = n0 + n2 * 32 + lo;
    float bv = bz[col];
#pragma unroll
    for (int q = 0; q < 4; ++q)
#pragma unroll
      for (int j = 0; j < 4; ++j) {
        size_t r = (size_t)(bm + w * 32 + j + q * 8 + g * 4);
        out[r * 256 + col] = (acc[n2][q * 4 + j] + bv) * st + inp[r * 256 + col];
      }
  }
}

extern "C" void kernel_launch(void* const* d_in, const int* in_sizes, int n_in,
                              void* d_out, int out_size, void* d_ws, size_t ws_size,
                              hipStream_t stream) {
  const float* inp   = (const float*)d_in[0];
  const float* bn1_g = (const float*)d_in[1];
  const float* bn1_b = (const float*)d_in[2];
  const float* bn1_m = (const float*)d_in[3];
  const float* bn1_v = (const float*)d_in[4];
  const float* bn2_g = (const float*)d_in[5];
  const float* bn2_b = (const float*)d_in[6];
  const float* bn2_m = (const float*)d_in[7];
  const float* bn2_v = (const float*)d_in[8];
  const float* W_g   = (const float*)d_in[9];
  const float* b_g   = (const float*)d_in[10];
  const float* W_th  = (const float*)d_in[11];
  const float* b_th  = (const float*)d_in[12];
  const float* W_ph  = (const float*)d_in[13];
  const float* b_ph  = (const float*)d_in[14];
  const float* W_z   = (const float*)d_in[15];
  const float* b_z   = (const float*)d_in[16];
  const float* sita  = (const float*)d_in[17];
  float* out = (float*)d_out;

  float* ws_f = (float*)d_ws;
  float* lp   = ws_f;                 // 4*32768
  float* bn1s = lp + 131072;          // 256
  float* bn1h = bn1s + 256;           // 256
  float* bn2s = bn1h + 256;           // 128
  float* bn2h = bn2s + 128;           // 128
  unsigned short* Opart = (unsigned short*)(bn2h + 128);  // 4*4194304 bf16
  unsigned short* Tb  = Opart + 16777216;                 // 4194304
  unsigned short* Gt2 = Tb + 4194304;                     // 2097152
  unsigned short* Pp2 = Gt2 + 2097152;                    // 2097152
  unsigned short* Wt3 = Pp2 + 2097152;                    // 98304
  unsigned short* Wzt = Wt3 + 98304;                      // 32768

  k_prepw<<<dim3(512), dim3(256), 0, stream>>>(W_th, W_g, W_ph, W_z,
                                               bn1_g, bn1_b, bn1_m, bn1_v,
                                               bn2_g, bn2_b, bn2_m, bn2_v,
                                               Wt3, Wzt, bn1s, bn1h, bn2s, bn2h);
  k_gemm3<<<dim3(256, 3), dim3(256), 0, stream>>>(inp, bn1s, bn1h, Wt3,
                                                  b_th, b_g, b_ph, Tb, Gt2, Pp2);
  k_attn<<<dim3(2048), dim3(128), 0, stream>>>(Tb, Pp2, Gt2, Opart, lp);
  k_gemm_z<<<dim3(256, 2), dim3(256), 0, stream>>>(Opart, lp, Wzt, b_z,
                                                   bn2s, bn2h, inp, sita, out);
}

// Round 7
// 222.841 us; speedup vs baseline: 5.8975x; 1.1279x over previous
//
#include <hip/hip_runtime.h>
#include <math.h>

#define BNEPS 1e-3f
#define LOG2E 1.44269504f

typedef __attribute__((ext_vector_type(8))) short bf8;
typedef __attribute__((ext_vector_type(8))) unsigned short u16x8;
typedef __attribute__((ext_vector_type(16))) float f32x16;
typedef __attribute__((ext_vector_type(2))) unsigned u32x2;

__device__ __forceinline__ unsigned short f2bf(float x) {
  unsigned u = __builtin_bit_cast(unsigned, x);
  unsigned r = (u + 0x7fffu + ((u >> 16) & 1u)) >> 16;
  return (unsigned short)r;
}
__device__ __forceinline__ float bf2f(unsigned short h) {
  return __builtin_bit_cast(float, ((unsigned)h) << 16);
}
__device__ __forceinline__ float exp2a(float x) {
  float r;
  asm("v_exp_f32 %0, %1" : "=v"(r) : "v"(x));
  return r;  // 2^x
}
// cheap elu: exp(v)-1 = 2^(v*log2e)-1 (abs err ~1e-7, far under bf16 quant)
__device__ __forceinline__ float eluf(float v) {
  return v > 0.f ? v : exp2a(v * LOG2E) - 1.f;
}
__device__ __forceinline__ unsigned cvtpk(float a, float b) {
  unsigned r;
  asm("v_cvt_pk_bf16_f32 %0, %1, %2" : "=v"(r) : "v"(a), "v"(b));
  return r;  // lo = bf16(a), hi = bf16(b)
}

#define GLDS(src, dst)                                                          \
  __builtin_amdgcn_global_load_lds(                                             \
      (const __attribute__((address_space(1))) unsigned int*)(src),             \
      (__attribute__((address_space(3))) unsigned int*)(dst), 16, 0, 0)

// ---------- prep: weights -> bf16 fragment-order Wfrag; Wzt [n][k]; bn scale/shift ----
// Wfrag element index: ((((t*4+ks)*2+g)*12 + f)*32 + lo)*8 + e
//   f: 0-3 theta, 4-7 g, 8-11 phi (n = (f&3)*32+lo); k = t*64+ks*16+g*8+e
__global__ __launch_bounds__(256) void k_prepw(
    const float* __restrict__ Wth, const float* __restrict__ Wg,
    const float* __restrict__ Wph, const float* __restrict__ Wz,
    const float* __restrict__ g1, const float* __restrict__ b1,
    const float* __restrict__ m1, const float* __restrict__ v1,
    const float* __restrict__ g2, const float* __restrict__ b2,
    const float* __restrict__ m2, const float* __restrict__ v2,
    unsigned short* __restrict__ Wfrag, unsigned short* __restrict__ Wzt,
    float* __restrict__ bn1s, float* __restrict__ bn1h,
    float* __restrict__ bn2s, float* __restrict__ bn2h)
{
  int id = blockIdx.x * 256 + threadIdx.x;
  if (id < 98304) {
    int e = id & 7, lo = (id >> 3) & 31;
    int fg = id >> 8;          // 0..383
    int f = fg % 12;
    int r = fg / 12;           // 0..31
    int g = r & 1, ks = (r >> 1) & 3, t = r >> 3;
    int sel = f >> 2, n2 = f & 3;
    int n = n2 * 32 + lo, k = t * 64 + ks * 16 + g * 8 + e;
    const float* W = (sel == 0) ? Wth : (sel == 1) ? Wg : Wph;
    Wfrag[id] = f2bf(W[(size_t)k * 128 + n]);
  } else {
    int rem = id - 98304;
    int n = rem >> 7, k = rem & 127;
    Wzt[rem] = f2bf(Wz[(size_t)k * 256 + n]);
  }
  if (id < 256) { float s = g1[id] * rsqrtf(v1[id] + BNEPS); bn1s[id] = s; bn1h[id] = b1[id] - m1[id] * s; }
  if (id < 128) { float s = g2[id] * rsqrtf(v2[id] + BNEPS); bn2s[id] = s; bn2h[id] = b2[id] - m2[id] * s; }
}

// ---------- GEMM3 one-pass: A (bn1+elu fused) staged ONCE, 3 outputs ----------
// BM=64, grid 512. B-frags read directly from L2-resident Wfrag (no B LDS).
// Waves 0,1: frags 0-5 (theta 0-3 + g 0-1); waves 2,3: frags 6-11 (g 2-3 + phi 0-3).
__global__ __launch_bounds__(256, 2) void k_gemm3(
    const float* __restrict__ inp, const float* __restrict__ bn1s,
    const float* __restrict__ bn1h, const unsigned short* __restrict__ Wfrag,
    const float* __restrict__ bth, const float* __restrict__ bg,
    const float* __restrict__ bph, unsigned short* __restrict__ Tb,
    unsigned short* __restrict__ Gt2, unsigned short* __restrict__ Pp2)
{
  __shared__ unsigned short As[64][72];
  __shared__ unsigned short Tt[64][136];
  __shared__ float2 bnsh[256];
  const int bm = blockIdx.x * 64;
  const int tid = threadIdx.x;
  const int w = tid >> 6, l = tid & 63;
  const int lo = l & 31, g = l >> 5;
  const int wm = w & 1, nb = (w >> 1) * 6;
  const int srow = tid >> 2, sq = tid & 3;
  if (tid < 256) bnsh[tid] = {bn1s[tid], bn1h[tid]};

  f32x16 acc[6];
#pragma unroll
  for (int i = 0; i < 6; ++i)
#pragma unroll
    for (int j = 0; j < 16; ++j) acc[i][j] = 0.f;

  for (int t = 0; t < 4; ++t) {
    __syncthreads();
    {
      const float* sa = inp + (size_t)(bm + srow) * 256 + t * 64 + sq * 16;
#pragma unroll
      for (int h = 0; h < 2; ++h) {
        float4 v0 = *(const float4*)(sa + h * 8);
        float4 v1 = *(const float4*)(sa + h * 8 + 4);
        int ch = t * 64 + sq * 16 + h * 8;
        float vv[8] = {v0.x, v0.y, v0.z, v0.w, v1.x, v1.y, v1.z, v1.w};
        u16x8 o;
#pragma unroll
        for (int u = 0; u < 8; ++u) {
          float2 sh = bnsh[ch + u];
          o[u] = f2bf(eluf(vv[u] * sh.x + sh.y));
        }
        *(u16x8*)&As[srow][sq * 16 + h * 8] = o;
      }
    }
    __syncthreads();
#pragma unroll
    for (int ks = 0; ks < 4; ++ks) {
      bf8 af = *(const bf8*)&As[wm * 32 + lo][ks * 16 + g * 8];
      const unsigned short* wf =
          Wfrag + (size_t)((((t * 4 + ks) * 2 + g) * 12 + nb) * 32 + lo) * 8;
#pragma unroll
      for (int fi = 0; fi < 6; ++fi) {
        bf8 bF = *(const bf8*)(wf + fi * 256);
        acc[fi] = __builtin_amdgcn_mfma_f32_32x32x16_bf16(af, bF, acc[fi], 0, 0, 0);
      }
    }
  }

  // epilogue: theta -> Tt (LDS transpose); g -> packed u32 scatter; phi -> 2B scatter
#pragma unroll
  for (int fi = 0; fi < 6; ++fi) {
    const int fg = nb + fi;
    if (fg < 4) {               // theta, pre-scaled by log2e for exp2 softmax
      int col = fg * 32 + lo;
      float bv = bth[col];
#pragma unroll
      for (int q = 0; q < 4; ++q)
#pragma unroll
        for (int j = 0; j < 4; ++j)
          Tt[wm * 32 + q * 8 + g * 4 + j][col] = f2bf((acc[fi][q * 4 + j] + bv) * LOG2E);
    } else if (fg < 8) {        // g: width-2 maxpool -> V^T chunk layout
      int col = (fg - 4) * 32 + lo;
      float bv = bg[col];
#pragma unroll
      for (int q = 0; q < 4; ++q) {
        float v0 = acc[fi][q * 4 + 0] + bv, v1 = acc[fi][q * 4 + 1] + bv;
        float v2 = acc[fi][q * 4 + 2] + bv, v3 = acc[fi][q * 4 + 3] + bv;
        float mx01 = fmaxf(v0, v1), mx23 = fmaxf(v2, v3);
        int r = bm + wm * 32 + q * 8 + g * 4;   // even row, j=0
        int pr = r >> 1;
        int b = pr >> 11, local = pr & 2047;
        int kb = local >> 5, sub = (local >> 3) & 3, m = local & 7;  // m even
        unsigned pk = cvtpk(mx01, mx23);
        *(unsigned*)&Gt2[((((size_t)b * 64 + kb) * 4 + sub) * 128 + col) * 8 + m] = pk;
      }
    } else {                    // phi: width-2 maxpool -> chunk layout
      int col = (fg - 8) * 32 + lo;
      float bv = bph[col];
      int csub = col >> 3, e = col & 7;
#pragma unroll
      for (int q = 0; q < 4; ++q) {
        float v0 = acc[fi][q * 4 + 0] + bv, v1 = acc[fi][q * 4 + 1] + bv;
        float v2 = acc[fi][q * 4 + 2] + bv, v3 = acc[fi][q * 4 + 3] + bv;
        float mx01 = fmaxf(v0, v1), mx23 = fmaxf(v2, v3);
        int r = bm + wm * 32 + q * 8 + g * 4;
        int pr = r >> 1;
        int b = pr >> 11, local = pr & 2047;
        int kb = local >> 5, kv = local & 31;   // kv even, kv+1 same kb
        size_t base = (((size_t)(b * 64 + kb) * 16 + csub) * 32 + kv) * 8 + e;
        Pp2[base] = f2bf(mx01);
        Pp2[base + 8] = f2bf(mx23);
      }
    }
  }
  __syncthreads();
  {  // coalesced theta store
    const int rr = tid >> 2, qq = tid & 3;
#pragma unroll
    for (int i = 0; i < 4; ++i) {
      u16x8 vv = *(u16x8*)&Tt[rr][qq * 32 + i * 8];
      *(u16x8*)&Tb[(size_t)(bm + rr) * 128 + qq * 32 + i * 8] = vv;
    }
  }
}

// ---------- MFMA flash attention: KV-split x4, kv-tile 32, global_load_lds staging ----------
// grid 2048: bid = ((split*64 + qt)*8) + b. Writes bf16 unnormalized O_part + fp32 l_part.
__global__ __launch_bounds__(128, 4) void k_attn(
    const unsigned short* __restrict__ T, const unsigned short* __restrict__ Pp2,
    const unsigned short* __restrict__ Gt2, unsigned short* __restrict__ Opart,
    float* __restrict__ lpart)
{
  __shared__ unsigned short phl[4096];   // [csub=ch>>3][kv 32][8ch]
  __shared__ unsigned short vtl[4096];   // [sub=kv>>3][ch 128][8kv]
  const int bid = blockIdx.x;
  const int b = bid & 7, qt = (bid >> 3) & 63, sp = bid >> 9;
  const int tid = threadIdx.x;
  const int w = tid >> 6, l = tid & 63;
  const int lo = l & 31, g = l >> 5;
  const int qr0 = qt * 64;

  const unsigned short* Tq = T + ((size_t)(b * 4096 + qr0 + w * 32 + lo)) * 128 + g * 8;
  bf8 qf[8];
#pragma unroll
  for (int ks = 0; ks < 8; ++ks) qf[ks] = *(const bf8*)(Tq + ks * 16);

  f32x16 oacc[4];
#pragma unroll
  for (int i = 0; i < 4; ++i)
#pragma unroll
    for (int j = 0; j < 16; ++j) oacc[i][j] = 0.f;
  float lrun = 0.f;

  const unsigned short* Pc = Pp2 + ((size_t)b * 64 + sp * 16) * 4096;
  const unsigned short* Gc = Gt2 + ((size_t)b * 64 + sp * 16) * 4096;

  for (int it = 0; it < 16; ++it) {
    const unsigned short* ps = Pc + (size_t)it * 4096 + w * 2048 + l * 8;
    const unsigned short* vs = Gc + (size_t)it * 4096 + w * 2048 + l * 8;
#pragma unroll
    for (int j = 0; j < 4; ++j) {
      GLDS(ps + j * 512, &phl[(w * 4 + j) * 512]);
      GLDS(vs + j * 512, &vtl[(w * 4 + j) * 512]);
    }
    __syncthreads();   // drains vmcnt -> LDS tile ready

    // S^T = phi_tile(32kv) x Q^T : lane holds 16 of 32 kv for q-row lo
    __builtin_amdgcn_s_setprio(1);
    f32x16 s0;
#pragma unroll
    for (int j = 0; j < 16; ++j) s0[j] = 0.f;
#pragma unroll
    for (int ks = 0; ks < 8; ++ks) {
      bf8 a0 = *(const bf8*)&phl[(ks * 2 + g) * 256 + lo * 8];
      s0 = __builtin_amdgcn_mfma_f32_32x32x16_bf16(a0, qf[ks], s0, 0, 0, 0);
    }
    __builtin_amdgcn_s_setprio(0);

    // no-max softmax: P = 2^(S') (theta pre-scaled by log2e)
#pragma unroll
    for (int r = 0; r < 16; ++r) { s0[r] = exp2a(s0[r]); lrun += s0[r]; }

    // PV: O^T += V^T x P^T ; half-exchange via v_permlane32_swap (VALU, no LDS)
    __builtin_amdgcn_s_setprio(1);
#pragma unroll
    for (int ks2 = 0; ks2 < 2; ++ks2) {
      const int base = 8 * ks2;
      unsigned uA0 = cvtpk(s0[base + 0], s0[base + 1]);
      unsigned uA1 = cvtpk(s0[base + 2], s0[base + 3]);
      unsigned uB0 = cvtpk(s0[base + 4], s0[base + 5]);
      unsigned uB1 = cvtpk(s0[base + 6], s0[base + 7]);
      unsigned sw0 = g ? uA0 : uB0;
      unsigned sw1 = g ? uA1 : uB1;
      unsigned a0 = sw0, b0 = sw0, a1 = sw1, b1 = sw1;
      asm("v_permlane32_swap_b32 %0, %1" : "+v"(a0), "+v"(b0));
      asm("v_permlane32_swap_b32 %0, %1" : "+v"(a1), "+v"(b1));
      unsigned r0 = g ? a0 : b0;
      unsigned r1 = g ? a1 : b1;
      union { bf8 v; unsigned u[4]; } pf;
      if (g == 0) { pf.u[0] = uA0; pf.u[1] = uA1; pf.u[2] = r0; pf.u[3] = r1; }
      else        { pf.u[0] = r0;  pf.u[1] = r1;  pf.u[2] = uB0; pf.u[3] = uB1; }
#pragma unroll
      for (int n2 = 0; n2 < 4; ++n2) {
        bf8 vf = *(const bf8*)&vtl[(ks2 * 2 + g) * 1024 + (n2 * 32 + lo) * 8];
        oacc[n2] = __builtin_amdgcn_mfma_f32_32x32x16_bf16(vf, pf.v, oacc[n2], 0, 0, 0);
      }
    }
    __builtin_amdgcn_s_setprio(0);
    __syncthreads();   // all waves done reading before next DMA overwrites
  }

  lrun += __shfl_xor(lrun, 32);
  const int qrow = qr0 + w * 32 + lo;
  unsigned short* Ob = Opart + (size_t)sp * 4194304 + ((size_t)(b * 4096 + qrow)) * 128;
#pragma unroll
  for (int n2 = 0; n2 < 4; ++n2)
#pragma unroll
    for (int q4 = 0; q4 < 4; ++q4) {
      unsigned u0 = cvtpk(oacc[n2][q4 * 4 + 0], oacc[n2][q4 * 4 + 1]);
      unsigned u1 = cvtpk(oacc[n2][q4 * 4 + 2], oacc[n2][q4 * 4 + 3]);
      u32x2 o = {u0, u1};
      *(u32x2*)&Ob[n2 * 32 + q4 * 8 + g * 4] = o;
    }
  if (g == 0) lpart[(size_t)sp * 32768 + b * 4096 + qrow] = lrun;
}

// ---------- final: out = (elu(bn2(sum(Opart)/suml)) @ Wz + bz)*sita + inp ----------
__global__ __launch_bounds__(256) void k_gemm_z(
    const unsigned short* __restrict__ Opart, const float* __restrict__ lp,
    const unsigned short* __restrict__ Wzt,
    const float* __restrict__ bz, const float* __restrict__ bn2s,
    const float* __restrict__ bn2h, const float* __restrict__ inp,
    const float* __restrict__ sita, float* __restrict__ out)
{
  __shared__ unsigned short As[128][72];
  __shared__ unsigned short Bs[128][72];
  const int bm = blockIdx.x * 128, n0 = blockIdx.y * 128;
  const int tid = threadIdx.x;
  const int l = tid & 63, w = tid >> 6, lo = l & 31, g = l >> 5;
  const int row = tid >> 1, hf = tid & 1;
  const size_t grow = (size_t)(bm + row);
  const float inv = 1.f / (lp[grow] + lp[32768 + grow] + lp[65536 + grow] + lp[98304 + grow]);
  f32x16 acc[4];
#pragma unroll
  for (int i = 0; i < 4; ++i)
#pragma unroll
    for (int j = 0; j < 16; ++j) acc[i][j] = 0.f;

  for (int k0 = 0; k0 < 128; k0 += 64) {
    __syncthreads();
    {
      unsigned short tmp[32];
#pragma unroll
      for (int i = 0; i < 4; ++i) {
        size_t off = grow * 128 + k0 + hf * 32 + i * 8;
        u16x8 p0 = *(const u16x8*)&Opart[off];
        u16x8 p1 = *(const u16x8*)&Opart[4194304 + off];
        u16x8 p2 = *(const u16x8*)&Opart[8388608 + off];
        u16x8 p3 = *(const u16x8*)&Opart[12582912 + off];
#pragma unroll
        for (int j = 0; j < 8; ++j) {
          int ch = k0 + hf * 32 + i * 8 + j;
          float y = (bf2f(p0[j]) + bf2f(p1[j]) + bf2f(p2[j]) + bf2f(p3[j])) * inv;
          tmp[i * 8 + j] = f2bf(eluf(y * bn2s[ch] + bn2h[ch]));
        }
      }
#pragma unroll
      for (int i = 0; i < 4; ++i)
        *(u16x8*)&As[row][hf * 32 + i * 8] = *(u16x8*)&tmp[i * 8];
      const unsigned short* sb = Wzt + (size_t)(n0 + row) * 128 + k0 + hf * 32;
#pragma unroll
      for (int i = 0; i < 4; ++i)
        *(u16x8*)&Bs[row][hf * 32 + i * 8] = *(const u16x8*)(sb + i * 8);
    }
    __syncthreads();
#pragma unroll
    for (int ks = 0; ks < 4; ++ks) {
      bf8 af = *(const bf8*)&As[w * 32 + lo][ks * 16 + g * 8];
#pragma unroll
      for (int n2 = 0; n2 < 4; ++n2) {
        bf8 bF = *(const bf8*)&Bs[n2 * 32 + lo][ks * 16 + g * 8];
        acc[n2] = __builtin_amdgcn_mfma_f32_32x32x16_bf16(af, bF, acc[n2], 0, 0, 0);
      }
    }
  }
  float st = sita[0];
#pragma unroll
  for (int n2 = 0; n2 < 4; ++n2) {
    int col = n0 + n2 * 32 + lo;
    float bv = bz[col];
#pragma unroll
    for (int q = 0; q < 4; ++q)
#pragma unroll
      for (int j = 0; j < 4; ++j) {
        size_t r = (size_t)(bm + w * 32 + j + q * 8 + g * 4);
        out[r * 256 + col] = (acc[n2][q * 4 + j] + bv) * st + inp[r * 256 + col];
      }
  }
}

extern "C" void kernel_launch(void* const* d_in, const int* in_sizes, int n_in,
                              void* d_out, int out_size, void* d_ws, size_t ws_size,
                              hipStream_t stream) {
  const float* inp   = (const float*)d_in[0];
  const float* bn1_g = (const float*)d_in[1];
  const float* bn1_b = (const float*)d_in[2];
  const float* bn1_m = (const float*)d_in[3];
  const float* bn1_v = (const float*)d_in[4];
  const float* bn2_g = (const float*)d_in[5];
  const float* bn2_b = (const float*)d_in[6];
  const float* bn2_m = (const float*)d_in[7];
  const float* bn2_v = (const float*)d_in[8];
  const float* W_g   = (const float*)d_in[9];
  const float* b_g   = (const float*)d_in[10];
  const float* W_th  = (const float*)d_in[11];
  const float* b_th  = (const float*)d_in[12];
  const float* W_ph  = (const float*)d_in[13];
  const float* b_ph  = (const float*)d_in[14];
  const float* W_z   = (const float*)d_in[15];
  const float* b_z   = (const float*)d_in[16];
  const float* sita  = (const float*)d_in[17];
  float* out = (float*)d_out;

  float* ws_f = (float*)d_ws;
  float* lp   = ws_f;                 // 4*32768
  float* bn1s = lp + 131072;          // 256
  float* bn1h = bn1s + 256;           // 256
  float* bn2s = bn1h + 256;           // 128
  float* bn2h = bn2s + 128;           // 128
  unsigned short* Opart = (unsigned short*)(bn2h + 128);  // 4*4194304 bf16
  unsigned short* Tb  = Opart + 16777216;                 // 4194304
  unsigned short* Gt2 = Tb + 4194304;                     // 2097152
  unsigned short* Pp2 = Gt2 + 2097152;                    // 2097152
  unsigned short* Wfr = Pp2 + 2097152;                    // 98304
  unsigned short* Wzt = Wfr + 98304;                      // 32768

  k_prepw<<<dim3(512), dim3(256), 0, stream>>>(W_th, W_g, W_ph, W_z,
                                               bn1_g, bn1_b, bn1_m, bn1_v,
                                               bn2_g, bn2_b, bn2_m, bn2_v,
                                               Wfr, Wzt, bn1s, bn1h, bn2s, bn2h);
  k_gemm3<<<dim3(512), dim3(256), 0, stream>>>(inp, bn1s, bn1h, Wfr,
                                               b_th, b_g, b_ph, Tb, Gt2, Pp2);
  k_attn<<<dim3(2048), dim3(128), 0, stream>>>(Tb, Pp2, Gt2, Opart, lp);
  k_gemm_z<<<dim3(256, 2), dim3(256), 0, stream>>>(Opart, lp, Wzt, b_z,
                                                   bn2s, bn2h, inp, sita, out);
}